// Round 13
// baseline (266.070 us; speedup 1.0000x reference)
//
#include <hip/hip_runtime.h>
#include <math.h>

// Problem constants
#define B_ 4
#define L_ 2048
#define D_ 256
#define H_ 8
#define DH_ 32
#define NH_ 32           // B*H
#define U_ 40
#define LD_ 524288       // L_*D_ floats per batch
#define NCH_ 16          // attention L-chunks

typedef __attribute__((ext_vector_type(8))) short short8;
typedef __attribute__((ext_vector_type(4))) float floatx4;

static __device__ __forceinline__ unsigned long long ullmin_(unsigned long long a, unsigned long long b) {
    return a < b ? a : b;
}
static __device__ __forceinline__ unsigned short f2bf_rne(float x) {
    unsigned u = __float_as_uint(x);
    unsigned r = u + 0x7FFFu + ((u >> 16) & 1u);
    return (unsigned short)(r >> 16);
}
static __device__ __forceinline__ float bf2f(unsigned short h) {
    return __uint_as_float(((unsigned)h) << 16);
}

// ---------------------------------------------------------------------------
// Batched projection GEMM with INLINE weight conversion.
// Grid (64, 4, 3): block = 128 rows x 64 cols; 768 blocks.
// 3-way-split bf16, 6 MFMA terms; per-dot err ~2e-7.
// ---------------------------------------------------------------------------
__global__ __launch_bounds__(256) void gemm_mfma3(const float* __restrict__ q,
                                                  const float* __restrict__ k,
                                                  const float* __restrict__ v,
                                                  const float* __restrict__ Wq,
                                                  const float* __restrict__ Wk,
                                                  const float* __restrict__ Wv,
                                                  const float* __restrict__ bq,
                                                  const float* __restrict__ bk,
                                                  const float* __restrict__ bv,
                                                  float* __restrict__ qp,
                                                  float* __restrict__ kp,
                                                  float* __restrict__ vp) {
    const int mat = blockIdx.z;
    const float* X = (mat == 0) ? q : (mat == 1) ? k : v;
    const float* W = (mat == 0) ? Wq : (mat == 1) ? Wk : Wv;
    const float* bias = (mat == 0) ? bq : (mat == 1) ? bk : bv;
    float* Y = (mat == 0) ? qp : (mat == 1) ? kp : vp;

    const int t = threadIdx.x;
    const int w = t >> 6, lane = t & 63;
    const int lq = lane & 15, quad = lane >> 4;
    const int colBase = blockIdx.y * 64;
    const int rowBaseW = blockIdx.x * 128 + w * 32;  // wave owns 2 m-tiles

    __shared__ unsigned short Bls[24576];  // 48 KB

    floatx4 acc[2][4];
#pragma unroll
    for (int mt = 0; mt < 2; ++mt)
#pragma unroll
        for (int nt = 0; nt < 4; ++nt) acc[mt][nt] = (floatx4){0.f, 0.f, 0.f, 0.f};

    for (int phase = 0; phase < 2; ++phase) {
        __syncthreads();
#pragma unroll
        for (int r = 0; r < 8; ++r) {
            const int e = t + 256 * r;      // 0..2047
            const int col = e >> 5;
            const int k4u = e & 31;
            const int kk = phase * 128 + k4u * 4;
            const float4 x = *(const float4*)(W + (size_t)(colBase + col) * 256 + kk);
            float xs[4] = {x.x, x.y, x.z, x.w};
            unsigned short hv[4], mv4[4], lv[4];
#pragma unroll
            for (int j = 0; j < 4; ++j) {
                hv[j] = f2bf_rne(xs[j]);
                const float e1 = xs[j] - bf2f(hv[j]);
                mv4[j] = f2bf_rne(e1);
                const float e2 = e1 - bf2f(mv4[j]);
                lv[j] = f2bf_rne(e2);
            }
            const int nt = col >> 4, cin = col & 15;
            const int ktl = k4u >> 3, kin = (k4u & 7) * 4;
            const int base = nt * 512 + cin * 32 + kin;
            *(ushort4*)&Bls[((0 * 4 + ktl) << 11) + base] = make_ushort4(hv[0], hv[1], hv[2], hv[3]);
            *(ushort4*)&Bls[((1 * 4 + ktl) << 11) + base] = make_ushort4(mv4[0], mv4[1], mv4[2], mv4[3]);
            *(ushort4*)&Bls[((2 * 4 + ktl) << 11) + base] = make_ushort4(lv[0], lv[1], lv[2], lv[3]);
        }
        __syncthreads();

#pragma unroll
        for (int ktl = 0; ktl < 4; ++ktl) {
            const int kt = phase * 4 + ktl;
            short8 Bh[4], Bm[4], Bl[4];
            const int fo = lq * 32 + quad * 8;
#pragma unroll
            for (int j = 0; j < 4; ++j) {
                Bh[j] = *(const short8*)&Bls[((0 * 4 + ktl) << 11) + j * 512 + fo];
                Bm[j] = *(const short8*)&Bls[((1 * 4 + ktl) << 11) + j * 512 + fo];
                Bl[j] = *(const short8*)&Bls[((2 * 4 + ktl) << 11) + j * 512 + fo];
            }
#pragma unroll
            for (int mt = 0; mt < 2; ++mt) {
                const int m = rowBaseW + mt * 16 + lq;
                short8 Ah, Am, Al;
                {
                    const float* xr = X + (size_t)m * 256 + kt * 32 + quad * 8;
                    const float4 x0 = *(const float4*)xr;
                    const float4 x1 = *(const float4*)(xr + 4);
                    float xs[8] = {x0.x, x0.y, x0.z, x0.w, x1.x, x1.y, x1.z, x1.w};
#pragma unroll
                    for (int j = 0; j < 8; ++j) {
                        const unsigned short h = f2bf_rne(xs[j]);
                        const float e1 = xs[j] - bf2f(h);
                        const unsigned short md = f2bf_rne(e1);
                        const float e2 = e1 - bf2f(md);
                        Ah[j] = (short)h;
                        Am[j] = (short)md;
                        Al[j] = (short)f2bf_rne(e2);
                    }
                }
#pragma unroll
                for (int j = 0; j < 4; ++j) {
                    floatx4 a = acc[mt][j];
                    a = __builtin_amdgcn_mfma_f32_16x16x32_bf16(Am, Bm[j], a, 0, 0, 0);
                    a = __builtin_amdgcn_mfma_f32_16x16x32_bf16(Ah, Bl[j], a, 0, 0, 0);
                    a = __builtin_amdgcn_mfma_f32_16x16x32_bf16(Al, Bh[j], a, 0, 0, 0);
                    a = __builtin_amdgcn_mfma_f32_16x16x32_bf16(Ah, Bm[j], a, 0, 0, 0);
                    a = __builtin_amdgcn_mfma_f32_16x16x32_bf16(Am, Bh[j], a, 0, 0, 0);
                    a = __builtin_amdgcn_mfma_f32_16x16x32_bf16(Ah, Bh[j], a, 0, 0, 0);
                    acc[mt][j] = a;
                }
            }
        }
    }

#pragma unroll
    for (int mt = 0; mt < 2; ++mt)
#pragma unroll
        for (int nt = 0; nt < 4; ++nt) {
            const int c = colBase + nt * 16 + lq;
            const float bv_ = bias[c];
#pragma unroll
            for (int r = 0; r < 4; ++r) {
                const int mr = rowBaseW + mt * 16 + quad * 4 + r;
                Y[(size_t)mr * 256 + c] = acc[mt][nt][r] + bv_;
            }
        }
}

// ---------------------------------------------------------------------------
// kconv + ksum partials, HIGH OCCUPANCY: 1024 blocks (i*32 + uc), 64 u each
// (round-12 version had 256 blocks = 1/CU -> latency-starved gathers).
// Ksum32[(i*32+uc)][d] partials, fixed order.
// ---------------------------------------------------------------------------
__global__ __launch_bounds__(256) void kconv_ksum(const float* __restrict__ kp,
                                                  const int* __restrict__ idx,
                                                  unsigned short* __restrict__ Khi,
                                                  unsigned short* __restrict__ Klo,
                                                  float* __restrict__ Ksum32) {
    const int blk = blockIdx.x;  // 1024: i*32 + uc
    const int i = blk >> 5, uc = blk & 31;
    const int b = i >> 3, h = i & 7;
    const int t = threadIdx.x;
    const int dq = (t & 7) * 4;
    const int ur = t >> 3;  // 0..31

    __shared__ float part[32][36];
    float ksum[4] = {0.f, 0.f, 0.f, 0.f};

#pragma unroll
    for (int p = 0; p < 2; ++p) {
        int u = uc * 64 + p * 32 + ur;
        const float4 x = *(const float4*)(kp + (size_t)b * LD_ + (size_t)idx[u] * D_ + h * DH_ + dq);
        float xs[4] = {x.x, x.y, x.z, x.w};
        unsigned short hv[4], lv[4];
#pragma unroll
        for (int j = 0; j < 4; ++j) {
            ksum[j] += xs[j];
            hv[j] = f2bf_rne(xs[j]);
            lv[j] = f2bf_rne(xs[j] - bf2f(hv[j]));
        }
        size_t o = ((size_t)i * 2048 + u) * 32 + dq;
        *(ushort4*)(Khi + o) = make_ushort4(hv[0], hv[1], hv[2], hv[3]);
        *(ushort4*)(Klo + o) = make_ushort4(lv[0], lv[1], lv[2], lv[3]);
    }
#pragma unroll
    for (int j = 0; j < 4; ++j) part[ur][dq + j] = ksum[j];
    __syncthreads();
    if (t < 32) {
        float s = 0.f;
#pragma unroll 8
        for (int u2 = 0; u2 < 32; ++u2) s += part[u2][t];
        Ksum32[(size_t)blk * 32 + t] = s;
    }
}

// ---------------------------------------------------------------------------
// Approx M-sweep on MFMA + fused Ssum reduce (32 partials) + mcombine.
// ---------------------------------------------------------------------------
__global__ __launch_bounds__(256) void mpart_mfma(const float* __restrict__ qp,
                                                  const unsigned short* __restrict__ Khi,
                                                  const unsigned short* __restrict__ Klo,
                                                  const float* __restrict__ Ksum32,
                                                  float* __restrict__ Mv,
                                                  float* __restrict__ Qmean) {
    const int blk = blockIdx.x;
    const int i = blk >> 5;
    const int lg = blk & 31;
    const int t = threadIdx.x;
    const int w = t >> 6;
    const int lane = t & 63;
    const int lq = lane & 15;
    const int quad = lane >> 4;

    __shared__ float ssum[32];
    __shared__ float red[4][64];
    if (t < 32) {
        float s = 0.f;
#pragma unroll 8
        for (int uc = 0; uc < 32; ++uc) s += Ksum32[((size_t)i * 32 + uc) * 32 + t];
        ssum[t] = s;
    }

    short8 Ah[4], Al[4];
#pragma unroll
    for (int lt = 0; lt < 4; ++lt) {
        const int l = lg * 64 + lt * 16 + lq;
        const float* qrow = qp + ((size_t)i * 2048 + l) * 32 + quad * 8;
        float4 x0 = *(const float4*)(qrow);
        float4 x1 = *(const float4*)(qrow + 4);
        float xs[8] = {x0.x, x0.y, x0.z, x0.w, x1.x, x1.y, x1.z, x1.w};
#pragma unroll
        for (int j = 0; j < 8; ++j) {
            unsigned short h = f2bf_rne(xs[j]);
            unsigned short lo = f2bf_rne(xs[j] - bf2f(h));
            Ah[lt][j] = (short)h;
            Al[lt][j] = (short)lo;
        }
    }

    floatx4 rmax[4];
#pragma unroll
    for (int lt = 0; lt < 4; ++lt)
        rmax[lt] = (floatx4){-INFINITY, -INFINITY, -INFINITY, -INFINITY};

    const size_t kfrag = ((size_t)i * 2048 + w * 512 + lq) * 32 + quad * 8;
    const unsigned short* ph = Khi + kfrag;
    const unsigned short* pl = Klo + kfrag;
#pragma unroll 2
    for (int s = 0; s < 32; ++s) {
        short8 Bh = *(const short8*)(ph + (size_t)s * 512);
        short8 Bl = *(const short8*)(pl + (size_t)s * 512);
#pragma unroll
        for (int lt = 0; lt < 4; ++lt) {
            floatx4 acc = (floatx4){0.f, 0.f, 0.f, 0.f};
            acc = __builtin_amdgcn_mfma_f32_16x16x32_bf16(Al[lt], Bh, acc, 0, 0, 0);
            acc = __builtin_amdgcn_mfma_f32_16x16x32_bf16(Ah[lt], Bl, acc, 0, 0, 0);
            acc = __builtin_amdgcn_mfma_f32_16x16x32_bf16(Ah[lt], Bh, acc, 0, 0, 0);
#pragma unroll
            for (int r = 0; r < 4; ++r) rmax[lt][r] = fmaxf(rmax[lt][r], acc[r]);
        }
    }

#pragma unroll
    for (int lt = 0; lt < 4; ++lt)
#pragma unroll
        for (int r = 0; r < 4; ++r) {
            float v = rmax[lt][r];
#pragma unroll
            for (int off = 1; off < 16; off <<= 1)
                v = fmaxf(v, __shfl_xor(v, off, 64));
            rmax[lt][r] = v;
        }
    if (lq == 0) {
#pragma unroll
        for (int lt = 0; lt < 4; ++lt)
#pragma unroll
            for (int r = 0; r < 4; ++r)
                red[w][lt * 16 + quad * 4 + r] = rmax[lt][r];
    }
    __syncthreads();
    if (t < 64) {
        const int l = lg * 64 + t;
        float m = fmaxf(fmaxf(red[0][t], red[1][t]), fmaxf(red[2][t], red[3][t]));
        const float4* q4 = (const float4*)(qp + ((size_t)i * 2048 + l) * 32);
        const float4* s4 = (const float4*)ssum;
        float qs = 0.f;
#pragma unroll
        for (int z = 0; z < 8; ++z) {
            float4 a = q4[z];
            float4 c = s4[z];
            qs = fmaf(a.x, c.x, qs);
            qs = fmaf(a.y, c.y, qs);
            qs = fmaf(a.z, c.z, qs);
            qs = fmaf(a.w, c.w, qs);
        }
        const float qm = qs * (1.0f / 2048.0f);
        Qmean[(size_t)i * 2048 + l] = qm;
        Mv[(size_t)i * 2048 + l] = m - qm;
    }
}

// ---------------------------------------------------------------------------
// Bottom-64 candidates per i from approx Mv. Keys in registers.
// ---------------------------------------------------------------------------
__global__ __launch_bounds__(256) void topk64_kernel(const float* __restrict__ Mv,
                                                     int* __restrict__ candIdx) {
    const int i = blockIdx.x;
    const int t = threadIdx.x;
    unsigned long long keys[8];
    __shared__ unsigned long long wred[4];
#pragma unroll
    for (int j = 0; j < 8; ++j) {
        const int l = t + 256 * j;
        unsigned u32 = __float_as_uint(Mv[(size_t)i * 2048 + l]);
        u32 = (u32 & 0x80000000u) ? ~u32 : (u32 | 0x80000000u);
        keys[j] = ((unsigned long long)u32 << 32) | (unsigned)l;
    }
    for (int it = 0; it < 64; ++it) {
        unsigned long long best = keys[0];
#pragma unroll
        for (int j = 1; j < 8; ++j) best = ullmin_(best, keys[j]);
#pragma unroll
        for (int off = 1; off < 64; off <<= 1)
            best = ullmin_(best, __shfl_xor(best, off, 64));
        if ((t & 63) == 0) wred[t >> 6] = best;
        __syncthreads();
        const unsigned long long m = ullmin_(ullmin_(wred[0], wred[1]), ullmin_(wred[2], wred[3]));
        if (t == 0) candIdx[i * 64 + it] = (int)(m & 0xffffffffu);
#pragma unroll
        for (int j = 0; j < 8; ++j)
            if (keys[j] == m) keys[j] = ~0ULL;
        __syncthreads();
    }
}

// ---------------------------------------------------------------------------
// Exact fp32 refine: grid 256 = i*8 + chunk (256 u each).
// ---------------------------------------------------------------------------
__global__ __launch_bounds__(256) void refine_kernel(const float* __restrict__ qp,
                                                     const float* __restrict__ kp,
                                                     const int* __restrict__ idx,
                                                     const int* __restrict__ candIdx,
                                                     float* __restrict__ refPart) {
    const int blk = blockIdx.x;  // 256
    const int i = blk >> 3, c = blk & 7;
    const int b = i >> 3, h = i & 7;
    const int t = threadIdx.x;
    __shared__ float qc[64][40];
    __shared__ float Ks[128][40];

    {
        const int cand = t >> 2, dp = (t & 3) * 8;
        const int l = candIdx[i * 64 + cand];
        const float* src = qp + ((size_t)i * 2048 + l) * 32 + dp;
        *(float4*)&qc[cand][dp] = *(const float4*)(src);
        *(float4*)&qc[cand][dp + 4] = *(const float4*)(src + 4);
    }
    __syncthreads();

    const int cand = t >> 2, usub = t & 3;
    float qv[32];
#pragma unroll
    for (int z = 0; z < 8; ++z) {
        float4 a = *(const float4*)&qc[cand][z * 4];
        qv[4 * z] = a.x; qv[4 * z + 1] = a.y; qv[4 * z + 2] = a.z; qv[4 * z + 3] = a.w;
    }

    float m = -INFINITY;
    for (int s = 0; s < 2; ++s) {
        {
            const int r = t >> 1, half = t & 1;
            const int u = c * 256 + s * 128 + r;
            const float* krow = kp + (size_t)b * LD_ + (size_t)idx[u] * D_ + h * DH_ + half * 16;
#pragma unroll
            for (int z = 0; z < 4; ++z)
                *(float4*)&Ks[r][half * 16 + z * 4] = *(const float4*)(krow + z * 4);
        }
        __syncthreads();
        for (int ur = usub; ur < 128; ur += 4) {
            float a0 = 0, a1 = 0, a2 = 0, a3 = 0;
#pragma unroll
            for (int z = 0; z < 8; ++z) {
                float4 kv = *(const float4*)&Ks[ur][z * 4];
                a0 = fmaf(qv[4 * z], kv.x, a0);
                a1 = fmaf(qv[4 * z + 1], kv.y, a1);
                a2 = fmaf(qv[4 * z + 2], kv.z, a2);
                a3 = fmaf(qv[4 * z + 3], kv.w, a3);
            }
            m = fmaxf(m, (a0 + a1) + (a2 + a3));
        }
        __syncthreads();
    }
    m = fmaxf(m, __shfl_xor(m, 1, 64));
    m = fmaxf(m, __shfl_xor(m, 2, 64));
    if ((t & 3) == 0) refPart[((size_t)i * 8 + c) * 64 + cand] = m;
}

// ---------------------------------------------------------------------------
// Final exact top-40 from 64 candidates (8 refine chunks). One wave per i.
// ---------------------------------------------------------------------------
__global__ __launch_bounds__(64) void select40_kernel(const int* __restrict__ candIdx,
                                                      const float* __restrict__ refPart,
                                                      const float* __restrict__ Qmean,
                                                      int* __restrict__ topIdx) {
    const int i = blockIdx.x;
    const int t = threadIdx.x;
    const int l = candIdx[i * 64 + t];
    float m = -INFINITY;
#pragma unroll
    for (int c = 0; c < 8; ++c) m = fmaxf(m, refPart[((size_t)i * 8 + c) * 64 + t]);
    float Mex = m - Qmean[(size_t)i * 2048 + l];
    unsigned u32 = __float_as_uint(Mex);
    u32 = (u32 & 0x80000000u) ? ~u32 : (u32 | 0x80000000u);
    unsigned long long key = ((unsigned long long)u32 << 32) | (unsigned)l;
    for (int it = 0; it < 40; ++it) {
        unsigned long long k2 = key;
#pragma unroll
        for (int off = 1; off < 64; off <<= 1) k2 = ullmin_(k2, __shfl_xor(k2, off, 64));
        if (key == k2) {
            topIdx[i * 40 + it] = l;
            key = ~0ULL;
        }
    }
}

// ---------------------------------------------------------------------------
// Flash-style attention, split over L into 16 chunks of 128 rows.
// Grid: 512 = i*16 + c, 320 threads (2 blocks/CU vs round-12's 1).
// Phase 1: thread (r = t>>1, half-of-j = t&1) -> all 256 lanes work.
// ---------------------------------------------------------------------------
#define SCP2 136  // sc row pad
#define VSP 36    // Vs row pad

__global__ __launch_bounds__(320) void attn_part(const float* __restrict__ qp,
                                                 const float* __restrict__ kp,
                                                 const float* __restrict__ vp,
                                                 const int* __restrict__ topIdx,
                                                 float* __restrict__ mPart,
                                                 float* __restrict__ sPart,
                                                 float* __restrict__ oPart) {
    const int blk = blockIdx.x;  // 512 = i*16 + c
    const int i = blk >> 4, c = blk & 15;
    const int b = i >> 3, h = i & 7;
    const int t = threadIdx.x;

    __shared__ float Qs[40][32];
    __shared__ float Vs[128][VSP];
    __shared__ float sc[40][SCP2];
    __shared__ float mred[40], sred[40];

    {
        const int r = t >> 3, qq = t & 7;
        const int lq = topIdx[i * 40 + r];
        *(float4*)&Qs[r][qq * 4] = *(const float4*)(qp + ((size_t)i * 2048 + lq) * 32 + qq * 4);
    }
    for (int e = t; e < 1024; e += 320) {
        const int r = e >> 3, qq = e & 7;
        *(float4*)&Vs[r][qq * 4] =
            *(const float4*)(vp + (size_t)b * LD_ + (size_t)(c * 128 + r) * 256 + h * 32 + qq * 4);
    }
    __syncthreads();

    const float scale = 0.17677669529663687f;  // 1/sqrt(32)

    if (t < 256) {
        const int r = t >> 1;          // K row within chunk
        const int j0 = (t & 1) * 20;   // half of the 40 queries
        const float* kr = kp + (size_t)b * LD_ + (size_t)(c * 128 + r) * 256 + h * 32;
        float kv[32];
#pragma unroll
        for (int z = 0; z < 8; ++z) {
            float4 x = *(const float4*)(kr + z * 4);
            kv[4 * z] = x.x; kv[4 * z + 1] = x.y; kv[4 * z + 2] = x.z; kv[4 * z + 3] = x.w;
        }
#pragma unroll 4
        for (int jj = 0; jj < 20; ++jj) {
            const int j = j0 + jj;
            float a0 = 0, a1 = 0, a2 = 0, a3 = 0;
#pragma unroll
            for (int z = 0; z < 8; ++z) {
                const float4 q4 = *(const float4*)&Qs[j][z * 4];
                a0 = fmaf(kv[4 * z], q4.x, a0);
                a1 = fmaf(kv[4 * z + 1], q4.y, a1);
                a2 = fmaf(kv[4 * z + 2], q4.z, a2);
                a3 = fmaf(kv[4 * z + 3], q4.w, a3);
            }
            sc[j][r] = ((a0 + a1) + (a2 + a3)) * scale;
        }
    }
    __syncthreads();

    {
        const int w = t >> 6, lane = t & 63;
#pragma unroll
        for (int rr = 0; rr < 8; ++rr) {
            const int j = w * 8 + rr;
            float x0 = sc[j][lane], x1 = sc[j][lane + 64];
            float m = fmaxf(x0, x1);
#pragma unroll
            for (int off = 1; off < 64; off <<= 1) m = fmaxf(m, __shfl_xor(m, off, 64));
            const float e0 = __expf(x0 - m), e1 = __expf(x1 - m);
            sc[j][lane] = e0; sc[j][lane + 64] = e1;
            float s = e0 + e1;
#pragma unroll
            for (int off = 1; off < 64; off <<= 1) s += __shfl_xor(s, off, 64);
            if (lane == 0) { mred[j] = m; sred[j] = s; }
        }
    }
    __syncthreads();

    {
        const int j = t >> 3, qq = t & 7;
        float4 acc = make_float4(0.f, 0.f, 0.f, 0.f);
        for (int l = 0; l < 128; ++l) {
            const float p = sc[j][l];
            const float4 v4 = *(const float4*)&Vs[l][qq * 4];
            acc.x = fmaf(p, v4.x, acc.x);
            acc.y = fmaf(p, v4.y, acc.y);
            acc.z = fmaf(p, v4.z, acc.z);
            acc.w = fmaf(p, v4.w, acc.w);
        }
        const size_t o = (size_t)(i * NCH_ + c) * 40 + j;
        *(float4*)&oPart[o * 32 + qq * 4] = acc;
        if (qq == 0) { mPart[o] = mred[j]; sPart[o] = sred[j]; }
    }
}

// ---------------------------------------------------------------------------
// FUSED attn_combine + output GEMM. Grid (4, 4): block = batch b's 40 rows
// x 64 cols. Combine the 16 chunk-partials into LDS Xs[40][258] (pad 258 ->
// <=2-way LDS conflicts, free), then 3-way-split MFMA GEMM with A from LDS.
// ---------------------------------------------------------------------------
__global__ __launch_bounds__(256) void gemm_out(const float* __restrict__ mPart,
                                                const float* __restrict__ sPart,
                                                const float* __restrict__ oPart,
                                                const float* __restrict__ Wc,
                                                const float* __restrict__ bias,
                                                float* __restrict__ out) {
    const int b = blockIdx.x;           // 0..3
    const int colBase = blockIdx.y * 64;
    const int t = threadIdx.x;
    const int w = t >> 6, lane = t & 63;
    const int lq = lane & 15, quad = lane >> 4;

    __shared__ float Xs[40][258];       // 41.3 KB
    __shared__ unsigned short Bls[24576];

    // ---- combine: 320 units (j, h) over 256 threads ----
    for (int e = t; e < 320; e += 256) {
        const int j = e >> 3, h = e & 7;
        const int i = b * 8 + h;
        const size_t base = (size_t)i * NCH_ * 40 + j;
        float mv[NCH_];
        float M = -INFINITY;
#pragma unroll
        for (int c = 0; c < NCH_; ++c) {
            mv[c] = mPart[base + (size_t)c * 40];
            M = fmaxf(M, mv[c]);
        }
        float wgt[NCH_];
        float S = 0.f;
#pragma unroll
        for (int c = 0; c < NCH_; ++c) {
            wgt[c] = __expf(mv[c] - M);
            S = fmaf(sPart[base + (size_t)c * 40], wgt[c], S);
        }
        const float invS = 1.0f / S;
#pragma unroll 4
        for (int d = 0; d < 32; ++d) {
            float O = 0.f;
#pragma unroll
            for (int c = 0; c < NCH_; ++c)
                O = fmaf(oPart[(base + (size_t)c * 40) * 32 + d], wgt[c], O);
            Xs[j][h * 32 + d] = O * invS;
        }
    }
    __syncthreads();

    floatx4 acc[3];
#pragma unroll
    for (int mt = 0; mt < 3; ++mt) acc[mt] = (floatx4){0.f, 0.f, 0.f, 0.f};

    for (int phase = 0; phase < 2; ++phase) {
        __syncthreads();
#pragma unroll
        for (int r = 0; r < 8; ++r) {
            const int e = t + 256 * r;
            const int col = e >> 5;
            const int k4u = e & 31;
            const int kk = phase * 128 + k4u * 4;
            const float4 x = *(const float4*)(Wc + (size_t)(colBase + col) * 256 + kk);
            float xs[4] = {x.x, x.y, x.z, x.w};
            unsigned short hv[4], mv4[4], lv[4];
#pragma unroll
            for (int j = 0; j < 4; ++j) {
                hv[j] = f2bf_rne(xs[j]);
                const float e1 = xs[j] - bf2f(hv[j]);
                mv4[j] = f2bf_rne(e1);
                const float e2 = e1 - bf2f(mv4[j]);
                lv[j] = f2bf_rne(e2);
            }
            const int nt = col >> 4, cin = col & 15;
            const int ktl = k4u >> 3, kin = (k4u & 7) * 4;
            const int base = nt * 512 + cin * 32 + kin;
            *(ushort4*)&Bls[((0 * 4 + ktl) << 11) + base] = make_ushort4(hv[0], hv[1], hv[2], hv[3]);
            *(ushort4*)&Bls[((1 * 4 + ktl) << 11) + base] = make_ushort4(mv4[0], mv4[1], mv4[2], mv4[3]);
            *(ushort4*)&Bls[((2 * 4 + ktl) << 11) + base] = make_ushort4(lv[0], lv[1], lv[2], lv[3]);
        }
        __syncthreads();

#pragma unroll
        for (int ktl = 0; ktl < 4; ++ktl) {
            const int kt = phase * 4 + ktl;
            // wave w owns n-tile nt = w
            short8 Bh, Bm, Bl;
            const int fo = w * 512 + lq * 32 + quad * 8;
            Bh = *(const short8*)&Bls[((0 * 4 + ktl) << 11) + fo];
            Bm = *(const short8*)&Bls[((1 * 4 + ktl) << 11) + fo];
            Bl = *(const short8*)&Bls[((2 * 4 + ktl) << 11) + fo];
#pragma unroll
            for (int mt = 0; mt < 3; ++mt) {
                const int m = mt * 16 + lq;
                short8 Ah, Am, Al;
                {
                    float xs[8] = {0.f, 0.f, 0.f, 0.f, 0.f, 0.f, 0.f, 0.f};
                    if (m < 40) {
                        const float* xr = &Xs[m][kt * 32 + quad * 8];
                        const float4 x0 = *(const float4*)xr;
                        const float4 x1 = *(const float4*)(xr + 4);
                        xs[0] = x0.x; xs[1] = x0.y; xs[2] = x0.z; xs[3] = x0.w;
                        xs[4] = x1.x; xs[5] = x1.y; xs[6] = x1.z; xs[7] = x1.w;
                    }
#pragma unroll
                    for (int j = 0; j < 8; ++j) {
                        const unsigned short h = f2bf_rne(xs[j]);
                        const float e1 = xs[j] - bf2f(h);
                        const unsigned short md = f2bf_rne(e1);
                        const float e2 = e1 - bf2f(md);
                        Ah[j] = (short)h;
                        Am[j] = (short)md;
                        Al[j] = (short)f2bf_rne(e2);
                    }
                }
                floatx4 a = acc[mt];
                a = __builtin_amdgcn_mfma_f32_16x16x32_bf16(Am, Bm, a, 0, 0, 0);
                a = __builtin_amdgcn_mfma_f32_16x16x32_bf16(Ah, Bl, a, 0, 0, 0);
                a = __builtin_amdgcn_mfma_f32_16x16x32_bf16(Al, Bh, a, 0, 0, 0);
                a = __builtin_amdgcn_mfma_f32_16x16x32_bf16(Ah, Bm, a, 0, 0, 0);
                a = __builtin_amdgcn_mfma_f32_16x16x32_bf16(Am, Bh, a, 0, 0, 0);
                a = __builtin_amdgcn_mfma_f32_16x16x32_bf16(Ah, Bh, a, 0, 0, 0);
                acc[mt] = a;
            }
        }
    }

    // C layout: col = lane&15, row = quad*4+reg; wave w covers cols w*16.
#pragma unroll
    for (int mt = 0; mt < 3; ++mt) {
        const int cc = colBase + w * 16 + lq;
        const float bv = bias[cc];
#pragma unroll
        for (int r = 0; r < 4; ++r) {
            const int ml = mt * 16 + quad * 4 + r;
            if (ml < 40) out[(size_t)(b * 40 + ml) * 256 + cc] = acc[mt][r] + bv;
        }
    }
}

// ---------------------------------------------------------------------------
extern "C" void kernel_launch(void* const* d_in, const int* in_sizes, int n_in,
                              void* d_out, int out_size, void* d_ws, size_t ws_size,
                              hipStream_t stream) {
    const float* q  = (const float*)d_in[0];
    const float* k  = (const float*)d_in[1];
    const float* v  = (const float*)d_in[2];
    const float* Wq = (const float*)d_in[3];
    const float* bq = (const float*)d_in[4];
    const float* Wk = (const float*)d_in[5];
    const float* bk = (const float*)d_in[6];
    const float* Wv = (const float*)d_in[7];
    const float* bv = (const float*)d_in[8];
    const float* Wc = (const float*)d_in[9];
    const float* bc = (const float*)d_in[10];
    const int* idx  = (const int*)d_in[11];
    float* out = (float*)d_out;

    // Workspace map (peak ~32.7 MB):
    //  [0,8)MB qp | [8,16) kp | [16,24) vp
    //  [24,28) Khi; later mPart/sPart/oPart (attn partials, 2.8 MB)
    //  [28,32) Klo
    //  32M+0 Mv(256K) | +256K Qmean(256K) | +512K Ksum32(128K)
    //  +640K candIdx(8K) | +648K topIdx(8K) | +656K refPart(64K)
    char* w = (char*)d_ws;
    float*          qp      = (float*)(w);
    float*          kp      = (float*)(w + (8u << 20));
    float*          vp      = (float*)(w + (16u << 20));
    unsigned short* Khi     = (unsigned short*)(w + (24u << 20));
    unsigned short* Klo     = (unsigned short*)(w + (28u << 20));
    float*          Mv      = (float*)(w + (32u << 20));
    float*          Qmean   = (float*)(w + (32u << 20) + (256u << 10));
    float*          Ksum32  = (float*)(w + (32u << 20) + (512u << 10));
    int*            candIdx = (int*)  (w + (32u << 20) + (640u << 10));
    int*            topIdx  = (int*)  (w + (32u << 20) + (648u << 10));
    float*          refPart = (float*)(w + (32u << 20) + (656u << 10));
    float*          mPart   = (float*)(w + (24u << 20));                // after mpart_mfma
    float*          sPart   = (float*)(w + (24u << 20) + (128u << 10));
    float*          oPart   = (float*)(w + (24u << 20) + (256u << 10)); // 2.62 MB

    // 8 launches.
    hipLaunchKernelGGL(gemm_mfma3, dim3(64, 4, 3), dim3(256), 0, stream,
                       q, k, v, Wq, Wk, Wv, bq, bk, bv, qp, kp, vp);
    hipLaunchKernelGGL(kconv_ksum, dim3(1024), dim3(256), 0, stream, kp, idx, Khi, Klo, Ksum32);
    hipLaunchKernelGGL(mpart_mfma, dim3(1024), dim3(256), 0, stream, qp, Khi, Klo, Ksum32, Mv, Qmean);
    hipLaunchKernelGGL(topk64_kernel, dim3(32), dim3(256), 0, stream, Mv, candIdx);
    hipLaunchKernelGGL(refine_kernel, dim3(256), dim3(256), 0, stream, qp, kp, idx, candIdx, refPart);
    hipLaunchKernelGGL(select40_kernel, dim3(32), dim3(64), 0, stream, candIdx, refPart, Qmean, topIdx);
    hipLaunchKernelGGL(attn_part, dim3(512), dim3(320), 0, stream, qp, kp, vp, topIdx, mPart, sPart, oPart);
    hipLaunchKernelGGL(gemm_out, dim3(4, 4), dim3(256), 0, stream, mPart, sPart, oPart, Wc, bc, out);
}

// Round 14
// 252.161 us; speedup vs baseline: 1.0552x; 1.0552x over previous
//
#include <hip/hip_runtime.h>
#include <math.h>

// Problem constants
#define B_ 4
#define L_ 2048
#define D_ 256
#define H_ 8
#define DH_ 32
#define NH_ 32           // B*H
#define U_ 40
#define LD_ 524288       // L_*D_ floats per batch
#define NCH_ 16          // attention L-chunks

typedef __attribute__((ext_vector_type(8))) short short8;
typedef __attribute__((ext_vector_type(4))) float floatx4;

static __device__ __forceinline__ unsigned long long ullmin_(unsigned long long a, unsigned long long b) {
    return a < b ? a : b;
}
static __device__ __forceinline__ unsigned short f2bf_rne(float x) {
    unsigned u = __float_as_uint(x);
    unsigned r = u + 0x7FFFu + ((u >> 16) & 1u);
    return (unsigned short)(r >> 16);
}
static __device__ __forceinline__ float bf2f(unsigned short h) {
    return __uint_as_float(((unsigned)h) << 16);
}

// ---------------------------------------------------------------------------
// Batched projection GEMM with INLINE weight conversion.
// Grid (64, 4, 3): block = 128 rows x 64 cols; 768 blocks.
// 3-way-split bf16, 6 MFMA terms; per-dot err ~2e-7.
// ---------------------------------------------------------------------------
__global__ __launch_bounds__(256) void gemm_mfma3(const float* __restrict__ q,
                                                  const float* __restrict__ k,
                                                  const float* __restrict__ v,
                                                  const float* __restrict__ Wq,
                                                  const float* __restrict__ Wk,
                                                  const float* __restrict__ Wv,
                                                  const float* __restrict__ bq,
                                                  const float* __restrict__ bk,
                                                  const float* __restrict__ bv,
                                                  float* __restrict__ qp,
                                                  float* __restrict__ kp,
                                                  float* __restrict__ vp) {
    const int mat = blockIdx.z;
    const float* X = (mat == 0) ? q : (mat == 1) ? k : v;
    const float* W = (mat == 0) ? Wq : (mat == 1) ? Wk : Wv;
    const float* bias = (mat == 0) ? bq : (mat == 1) ? bk : bv;
    float* Y = (mat == 0) ? qp : (mat == 1) ? kp : vp;

    const int t = threadIdx.x;
    const int w = t >> 6, lane = t & 63;
    const int lq = lane & 15, quad = lane >> 4;
    const int colBase = blockIdx.y * 64;
    const int rowBaseW = blockIdx.x * 128 + w * 32;  // wave owns 2 m-tiles

    __shared__ unsigned short Bls[24576];  // 48 KB

    floatx4 acc[2][4];
#pragma unroll
    for (int mt = 0; mt < 2; ++mt)
#pragma unroll
        for (int nt = 0; nt < 4; ++nt) acc[mt][nt] = (floatx4){0.f, 0.f, 0.f, 0.f};

    for (int phase = 0; phase < 2; ++phase) {
        __syncthreads();
#pragma unroll
        for (int r = 0; r < 8; ++r) {
            const int e = t + 256 * r;      // 0..2047
            const int col = e >> 5;
            const int k4u = e & 31;
            const int kk = phase * 128 + k4u * 4;
            const float4 x = *(const float4*)(W + (size_t)(colBase + col) * 256 + kk);
            float xs[4] = {x.x, x.y, x.z, x.w};
            unsigned short hv[4], mv4[4], lv[4];
#pragma unroll
            for (int j = 0; j < 4; ++j) {
                hv[j] = f2bf_rne(xs[j]);
                const float e1 = xs[j] - bf2f(hv[j]);
                mv4[j] = f2bf_rne(e1);
                const float e2 = e1 - bf2f(mv4[j]);
                lv[j] = f2bf_rne(e2);
            }
            const int nt = col >> 4, cin = col & 15;
            const int ktl = k4u >> 3, kin = (k4u & 7) * 4;
            const int base = nt * 512 + cin * 32 + kin;
            *(ushort4*)&Bls[((0 * 4 + ktl) << 11) + base] = make_ushort4(hv[0], hv[1], hv[2], hv[3]);
            *(ushort4*)&Bls[((1 * 4 + ktl) << 11) + base] = make_ushort4(mv4[0], mv4[1], mv4[2], mv4[3]);
            *(ushort4*)&Bls[((2 * 4 + ktl) << 11) + base] = make_ushort4(lv[0], lv[1], lv[2], lv[3]);
        }
        __syncthreads();

#pragma unroll
        for (int ktl = 0; ktl < 4; ++ktl) {
            const int kt = phase * 4 + ktl;
            short8 Bh[4], Bm[4], Bl[4];
            const int fo = lq * 32 + quad * 8;
#pragma unroll
            for (int j = 0; j < 4; ++j) {
                Bh[j] = *(const short8*)&Bls[((0 * 4 + ktl) << 11) + j * 512 + fo];
                Bm[j] = *(const short8*)&Bls[((1 * 4 + ktl) << 11) + j * 512 + fo];
                Bl[j] = *(const short8*)&Bls[((2 * 4 + ktl) << 11) + j * 512 + fo];
            }
#pragma unroll
            for (int mt = 0; mt < 2; ++mt) {
                const int m = rowBaseW + mt * 16 + lq;
                short8 Ah, Am, Al;
                {
                    const float* xr = X + (size_t)m * 256 + kt * 32 + quad * 8;
                    const float4 x0 = *(const float4*)xr;
                    const float4 x1 = *(const float4*)(xr + 4);
                    float xs[8] = {x0.x, x0.y, x0.z, x0.w, x1.x, x1.y, x1.z, x1.w};
#pragma unroll
                    for (int j = 0; j < 8; ++j) {
                        const unsigned short h = f2bf_rne(xs[j]);
                        const float e1 = xs[j] - bf2f(h);
                        const unsigned short md = f2bf_rne(e1);
                        const float e2 = e1 - bf2f(md);
                        Ah[j] = (short)h;
                        Am[j] = (short)md;
                        Al[j] = (short)f2bf_rne(e2);
                    }
                }
#pragma unroll
                for (int j = 0; j < 4; ++j) {
                    floatx4 a = acc[mt][j];
                    a = __builtin_amdgcn_mfma_f32_16x16x32_bf16(Am, Bm[j], a, 0, 0, 0);
                    a = __builtin_amdgcn_mfma_f32_16x16x32_bf16(Ah, Bl[j], a, 0, 0, 0);
                    a = __builtin_amdgcn_mfma_f32_16x16x32_bf16(Al, Bh[j], a, 0, 0, 0);
                    a = __builtin_amdgcn_mfma_f32_16x16x32_bf16(Ah, Bm[j], a, 0, 0, 0);
                    a = __builtin_amdgcn_mfma_f32_16x16x32_bf16(Am, Bh[j], a, 0, 0, 0);
                    a = __builtin_amdgcn_mfma_f32_16x16x32_bf16(Ah, Bh[j], a, 0, 0, 0);
                    acc[mt][j] = a;
                }
            }
        }
    }

#pragma unroll
    for (int mt = 0; mt < 2; ++mt)
#pragma unroll
        for (int nt = 0; nt < 4; ++nt) {
            const int c = colBase + nt * 16 + lq;
            const float bv_ = bias[c];
#pragma unroll
            for (int r = 0; r < 4; ++r) {
                const int mr = rowBaseW + mt * 16 + quad * 4 + r;
                Y[(size_t)mr * 256 + c] = acc[mt][nt][r] + bv_;
            }
        }
}

// ---------------------------------------------------------------------------
// Final-projection GEMM (M=160), inline Wc conversion, bounds-checked.
// Grid (2, 4), 256 threads (round-12 version; round-13's combine-fused
// variant was 61 us at 0.7% occupancy -- reverted).
// ---------------------------------------------------------------------------
__global__ __launch_bounds__(256) void gemm_out(const float* __restrict__ X,
                                                const float* __restrict__ Wc,
                                                const float* __restrict__ bias,
                                                float* __restrict__ Y) {
    const int t = threadIdx.x;
    const int w = t >> 6, lane = t & 63;
    const int lq = lane & 15, quad = lane >> 4;
    const int colBase = blockIdx.y * 64;
    const int rowBaseW = blockIdx.x * 128 + w * 32;

    __shared__ unsigned short Bls[24576];

    floatx4 acc[2][4];
#pragma unroll
    for (int mt = 0; mt < 2; ++mt)
#pragma unroll
        for (int nt = 0; nt < 4; ++nt) acc[mt][nt] = (floatx4){0.f, 0.f, 0.f, 0.f};

    for (int phase = 0; phase < 2; ++phase) {
        __syncthreads();
#pragma unroll
        for (int r = 0; r < 8; ++r) {
            const int e = t + 256 * r;
            const int col = e >> 5;
            const int k4u = e & 31;
            const int kk = phase * 128 + k4u * 4;
            const float4 x = *(const float4*)(Wc + (size_t)(colBase + col) * 256 + kk);
            float xs[4] = {x.x, x.y, x.z, x.w};
            unsigned short hv[4], mv4[4], lv[4];
#pragma unroll
            for (int j = 0; j < 4; ++j) {
                hv[j] = f2bf_rne(xs[j]);
                const float e1 = xs[j] - bf2f(hv[j]);
                mv4[j] = f2bf_rne(e1);
                const float e2 = e1 - bf2f(mv4[j]);
                lv[j] = f2bf_rne(e2);
            }
            const int nt = col >> 4, cin = col & 15;
            const int ktl = k4u >> 3, kin = (k4u & 7) * 4;
            const int base = nt * 512 + cin * 32 + kin;
            *(ushort4*)&Bls[((0 * 4 + ktl) << 11) + base] = make_ushort4(hv[0], hv[1], hv[2], hv[3]);
            *(ushort4*)&Bls[((1 * 4 + ktl) << 11) + base] = make_ushort4(mv4[0], mv4[1], mv4[2], mv4[3]);
            *(ushort4*)&Bls[((2 * 4 + ktl) << 11) + base] = make_ushort4(lv[0], lv[1], lv[2], lv[3]);
        }
        __syncthreads();

#pragma unroll
        for (int ktl = 0; ktl < 4; ++ktl) {
            const int kt = phase * 4 + ktl;
            short8 Bh[4], Bm[4], Bl[4];
            const int fo = lq * 32 + quad * 8;
#pragma unroll
            for (int j = 0; j < 4; ++j) {
                Bh[j] = *(const short8*)&Bls[((0 * 4 + ktl) << 11) + j * 512 + fo];
                Bm[j] = *(const short8*)&Bls[((1 * 4 + ktl) << 11) + j * 512 + fo];
                Bl[j] = *(const short8*)&Bls[((2 * 4 + ktl) << 11) + j * 512 + fo];
            }
#pragma unroll
            for (int mt = 0; mt < 2; ++mt) {
                const int m = rowBaseW + mt * 16 + lq;
                short8 Ah, Am, Al;
                {
                    float xs[8] = {0.f, 0.f, 0.f, 0.f, 0.f, 0.f, 0.f, 0.f};
                    if (m < 160) {
                        const float* xr = X + (size_t)m * 256 + kt * 32 + quad * 8;
                        const float4 x0 = *(const float4*)xr;
                        const float4 x1 = *(const float4*)(xr + 4);
                        xs[0] = x0.x; xs[1] = x0.y; xs[2] = x0.z; xs[3] = x0.w;
                        xs[4] = x1.x; xs[5] = x1.y; xs[6] = x1.z; xs[7] = x1.w;
                    }
#pragma unroll
                    for (int j = 0; j < 8; ++j) {
                        const unsigned short h = f2bf_rne(xs[j]);
                        const float e1 = xs[j] - bf2f(h);
                        const unsigned short md = f2bf_rne(e1);
                        const float e2 = e1 - bf2f(md);
                        Ah[j] = (short)h;
                        Am[j] = (short)md;
                        Al[j] = (short)f2bf_rne(e2);
                    }
                }
#pragma unroll
                for (int j = 0; j < 4; ++j) {
                    floatx4 a = acc[mt][j];
                    a = __builtin_amdgcn_mfma_f32_16x16x32_bf16(Am, Bm[j], a, 0, 0, 0);
                    a = __builtin_amdgcn_mfma_f32_16x16x32_bf16(Ah, Bl[j], a, 0, 0, 0);
                    a = __builtin_amdgcn_mfma_f32_16x16x32_bf16(Al, Bh[j], a, 0, 0, 0);
                    a = __builtin_amdgcn_mfma_f32_16x16x32_bf16(Ah, Bm[j], a, 0, 0, 0);
                    a = __builtin_amdgcn_mfma_f32_16x16x32_bf16(Am, Bh[j], a, 0, 0, 0);
                    a = __builtin_amdgcn_mfma_f32_16x16x32_bf16(Ah, Bh[j], a, 0, 0, 0);
                    acc[mt][j] = a;
                }
            }
        }
    }

#pragma unroll
    for (int mt = 0; mt < 2; ++mt)
#pragma unroll
        for (int nt = 0; nt < 4; ++nt) {
            const int c = colBase + nt * 16 + lq;
            const float bv = bias[c];
#pragma unroll
            for (int r = 0; r < 4; ++r) {
                const int mr = rowBaseW + mt * 16 + quad * 4 + r;
                if (mr < 160) Y[(size_t)mr * 256 + c] = acc[mt][nt][r] + bv;
            }
        }
}

// ---------------------------------------------------------------------------
// kconv + ksum partials, 1024 blocks (i*32 + uc), 64 u each.
// ---------------------------------------------------------------------------
__global__ __launch_bounds__(256) void kconv_ksum(const float* __restrict__ kp,
                                                  const int* __restrict__ idx,
                                                  unsigned short* __restrict__ Khi,
                                                  unsigned short* __restrict__ Klo,
                                                  float* __restrict__ Ksum32) {
    const int blk = blockIdx.x;  // 1024: i*32 + uc
    const int i = blk >> 5, uc = blk & 31;
    const int b = i >> 3, h = i & 7;
    const int t = threadIdx.x;
    const int dq = (t & 7) * 4;
    const int ur = t >> 3;  // 0..31

    __shared__ float part[32][36];
    float ksum[4] = {0.f, 0.f, 0.f, 0.f};

#pragma unroll
    for (int p = 0; p < 2; ++p) {
        int u = uc * 64 + p * 32 + ur;
        const float4 x = *(const float4*)(kp + (size_t)b * LD_ + (size_t)idx[u] * D_ + h * DH_ + dq);
        float xs[4] = {x.x, x.y, x.z, x.w};
        unsigned short hv[4], lv[4];
#pragma unroll
        for (int j = 0; j < 4; ++j) {
            ksum[j] += xs[j];
            hv[j] = f2bf_rne(xs[j]);
            lv[j] = f2bf_rne(xs[j] - bf2f(hv[j]));
        }
        size_t o = ((size_t)i * 2048 + u) * 32 + dq;
        *(ushort4*)(Khi + o) = make_ushort4(hv[0], hv[1], hv[2], hv[3]);
        *(ushort4*)(Klo + o) = make_ushort4(lv[0], lv[1], lv[2], lv[3]);
    }
#pragma unroll
    for (int j = 0; j < 4; ++j) part[ur][dq + j] = ksum[j];
    __syncthreads();
    if (t < 32) {
        float s = 0.f;
#pragma unroll 8
        for (int u2 = 0; u2 < 32; ++u2) s += part[u2][t];
        Ksum32[(size_t)blk * 32 + t] = s;
    }
}

// ---------------------------------------------------------------------------
// Approx M-sweep on MFMA + fused Ssum reduce (32 partials) + mcombine.
// ---------------------------------------------------------------------------
__global__ __launch_bounds__(256) void mpart_mfma(const float* __restrict__ qp,
                                                  const unsigned short* __restrict__ Khi,
                                                  const unsigned short* __restrict__ Klo,
                                                  const float* __restrict__ Ksum32,
                                                  float* __restrict__ Mv,
                                                  float* __restrict__ Qmean) {
    const int blk = blockIdx.x;
    const int i = blk >> 5;
    const int lg = blk & 31;
    const int t = threadIdx.x;
    const int w = t >> 6;
    const int lane = t & 63;
    const int lq = lane & 15;
    const int quad = lane >> 4;

    __shared__ float ssum[32];
    __shared__ float red[4][64];
    if (t < 32) {
        float s = 0.f;
#pragma unroll 8
        for (int uc = 0; uc < 32; ++uc) s += Ksum32[((size_t)i * 32 + uc) * 32 + t];
        ssum[t] = s;
    }

    short8 Ah[4], Al[4];
#pragma unroll
    for (int lt = 0; lt < 4; ++lt) {
        const int l = lg * 64 + lt * 16 + lq;
        const float* qrow = qp + ((size_t)i * 2048 + l) * 32 + quad * 8;
        float4 x0 = *(const float4*)(qrow);
        float4 x1 = *(const float4*)(qrow + 4);
        float xs[8] = {x0.x, x0.y, x0.z, x0.w, x1.x, x1.y, x1.z, x1.w};
#pragma unroll
        for (int j = 0; j < 8; ++j) {
            unsigned short h = f2bf_rne(xs[j]);
            unsigned short lo = f2bf_rne(xs[j] - bf2f(h));
            Ah[lt][j] = (short)h;
            Al[lt][j] = (short)lo;
        }
    }

    floatx4 rmax[4];
#pragma unroll
    for (int lt = 0; lt < 4; ++lt)
        rmax[lt] = (floatx4){-INFINITY, -INFINITY, -INFINITY, -INFINITY};

    const size_t kfrag = ((size_t)i * 2048 + w * 512 + lq) * 32 + quad * 8;
    const unsigned short* ph = Khi + kfrag;
    const unsigned short* pl = Klo + kfrag;
#pragma unroll 2
    for (int s = 0; s < 32; ++s) {
        short8 Bh = *(const short8*)(ph + (size_t)s * 512);
        short8 Bl = *(const short8*)(pl + (size_t)s * 512);
#pragma unroll
        for (int lt = 0; lt < 4; ++lt) {
            floatx4 acc = (floatx4){0.f, 0.f, 0.f, 0.f};
            acc = __builtin_amdgcn_mfma_f32_16x16x32_bf16(Al[lt], Bh, acc, 0, 0, 0);
            acc = __builtin_amdgcn_mfma_f32_16x16x32_bf16(Ah[lt], Bl, acc, 0, 0, 0);
            acc = __builtin_amdgcn_mfma_f32_16x16x32_bf16(Ah[lt], Bh, acc, 0, 0, 0);
#pragma unroll
            for (int r = 0; r < 4; ++r) rmax[lt][r] = fmaxf(rmax[lt][r], acc[r]);
        }
    }

#pragma unroll
    for (int lt = 0; lt < 4; ++lt)
#pragma unroll
        for (int r = 0; r < 4; ++r) {
            float v = rmax[lt][r];
#pragma unroll
            for (int off = 1; off < 16; off <<= 1)
                v = fmaxf(v, __shfl_xor(v, off, 64));
            rmax[lt][r] = v;
        }
    if (lq == 0) {
#pragma unroll
        for (int lt = 0; lt < 4; ++lt)
#pragma unroll
            for (int r = 0; r < 4; ++r)
                red[w][lt * 16 + quad * 4 + r] = rmax[lt][r];
    }
    __syncthreads();
    if (t < 64) {
        const int l = lg * 64 + t;
        float m = fmaxf(fmaxf(red[0][t], red[1][t]), fmaxf(red[2][t], red[3][t]));
        const float4* q4 = (const float4*)(qp + ((size_t)i * 2048 + l) * 32);
        const float4* s4 = (const float4*)ssum;
        float qs = 0.f;
#pragma unroll
        for (int z = 0; z < 8; ++z) {
            float4 a = q4[z];
            float4 c = s4[z];
            qs = fmaf(a.x, c.x, qs);
            qs = fmaf(a.y, c.y, qs);
            qs = fmaf(a.z, c.z, qs);
            qs = fmaf(a.w, c.w, qs);
        }
        const float qm = qs * (1.0f / 2048.0f);
        Qmean[(size_t)i * 2048 + l] = qm;
        Mv[(size_t)i * 2048 + l] = m - qm;
    }
}

// ---------------------------------------------------------------------------
// Bottom-64 candidates per i from approx Mv. Keys in registers.
// ---------------------------------------------------------------------------
__global__ __launch_bounds__(256) void topk64_kernel(const float* __restrict__ Mv,
                                                     int* __restrict__ candIdx) {
    const int i = blockIdx.x;
    const int t = threadIdx.x;
    unsigned long long keys[8];
    __shared__ unsigned long long wred[4];
#pragma unroll
    for (int j = 0; j < 8; ++j) {
        const int l = t + 256 * j;
        unsigned u32 = __float_as_uint(Mv[(size_t)i * 2048 + l]);
        u32 = (u32 & 0x80000000u) ? ~u32 : (u32 | 0x80000000u);
        keys[j] = ((unsigned long long)u32 << 32) | (unsigned)l;
    }
    for (int it = 0; it < 64; ++it) {
        unsigned long long best = keys[0];
#pragma unroll
        for (int j = 1; j < 8; ++j) best = ullmin_(best, keys[j]);
#pragma unroll
        for (int off = 1; off < 64; off <<= 1)
            best = ullmin_(best, __shfl_xor(best, off, 64));
        if ((t & 63) == 0) wred[t >> 6] = best;
        __syncthreads();
        const unsigned long long m = ullmin_(ullmin_(wred[0], wred[1]), ullmin_(wred[2], wred[3]));
        if (t == 0) candIdx[i * 64 + it] = (int)(m & 0xffffffffu);
#pragma unroll
        for (int j = 0; j < 8; ++j)
            if (keys[j] == m) keys[j] = ~0ULL;
        __syncthreads();
    }
}

// ---------------------------------------------------------------------------
// Exact fp32 refine: grid 256 = i*8 + chunk (256 u each).
// ---------------------------------------------------------------------------
__global__ __launch_bounds__(256) void refine_kernel(const float* __restrict__ qp,
                                                     const float* __restrict__ kp,
                                                     const int* __restrict__ idx,
                                                     const int* __restrict__ candIdx,
                                                     float* __restrict__ refPart) {
    const int blk = blockIdx.x;  // 256
    const int i = blk >> 3, c = blk & 7;
    const int b = i >> 3, h = i & 7;
    const int t = threadIdx.x;
    __shared__ float qc[64][40];
    __shared__ float Ks[128][40];

    {
        const int cand = t >> 2, dp = (t & 3) * 8;
        const int l = candIdx[i * 64 + cand];
        const float* src = qp + ((size_t)i * 2048 + l) * 32 + dp;
        *(float4*)&qc[cand][dp] = *(const float4*)(src);
        *(float4*)&qc[cand][dp + 4] = *(const float4*)(src + 4);
    }
    __syncthreads();

    const int cand = t >> 2, usub = t & 3;
    float qv[32];
#pragma unroll
    for (int z = 0; z < 8; ++z) {
        float4 a = *(const float4*)&qc[cand][z * 4];
        qv[4 * z] = a.x; qv[4 * z + 1] = a.y; qv[4 * z + 2] = a.z; qv[4 * z + 3] = a.w;
    }

    float m = -INFINITY;
    for (int s = 0; s < 2; ++s) {
        {
            const int r = t >> 1, half = t & 1;
            const int u = c * 256 + s * 128 + r;
            const float* krow = kp + (size_t)b * LD_ + (size_t)idx[u] * D_ + h * DH_ + half * 16;
#pragma unroll
            for (int z = 0; z < 4; ++z)
                *(float4*)&Ks[r][half * 16 + z * 4] = *(const float4*)(krow + z * 4);
        }
        __syncthreads();
        for (int ur = usub; ur < 128; ur += 4) {
            float a0 = 0, a1 = 0, a2 = 0, a3 = 0;
#pragma unroll
            for (int z = 0; z < 8; ++z) {
                float4 kv = *(const float4*)&Ks[ur][z * 4];
                a0 = fmaf(qv[4 * z], kv.x, a0);
                a1 = fmaf(qv[4 * z + 1], kv.y, a1);
                a2 = fmaf(qv[4 * z + 2], kv.z, a2);
                a3 = fmaf(qv[4 * z + 3], kv.w, a3);
            }
            m = fmaxf(m, (a0 + a1) + (a2 + a3));
        }
        __syncthreads();
    }
    m = fmaxf(m, __shfl_xor(m, 1, 64));
    m = fmaxf(m, __shfl_xor(m, 2, 64));
    if ((t & 3) == 0) refPart[((size_t)i * 8 + c) * 64 + cand] = m;
}

// ---------------------------------------------------------------------------
// Final exact top-40 from 64 candidates (8 refine chunks). One wave per i.
// ---------------------------------------------------------------------------
__global__ __launch_bounds__(64) void select40_kernel(const int* __restrict__ candIdx,
                                                      const float* __restrict__ refPart,
                                                      const float* __restrict__ Qmean,
                                                      int* __restrict__ topIdx) {
    const int i = blockIdx.x;
    const int t = threadIdx.x;
    const int l = candIdx[i * 64 + t];
    float m = -INFINITY;
#pragma unroll
    for (int c = 0; c < 8; ++c) m = fmaxf(m, refPart[((size_t)i * 8 + c) * 64 + t]);
    float Mex = m - Qmean[(size_t)i * 2048 + l];
    unsigned u32 = __float_as_uint(Mex);
    u32 = (u32 & 0x80000000u) ? ~u32 : (u32 | 0x80000000u);
    unsigned long long key = ((unsigned long long)u32 << 32) | (unsigned)l;
    for (int it = 0; it < 40; ++it) {
        unsigned long long k2 = key;
#pragma unroll
        for (int off = 1; off < 64; off <<= 1) k2 = ullmin_(k2, __shfl_xor(k2, off, 64));
        if (key == k2) {
            topIdx[i * 40 + it] = l;
            key = ~0ULL;
        }
    }
}

// ---------------------------------------------------------------------------
// Flash-style attention, split over L into 16 chunks of 128 rows.
// Grid: 512 = i*16 + c, 320 threads.
// ---------------------------------------------------------------------------
#define SCP2 136  // sc row pad
#define VSP 36    // Vs row pad

__global__ __launch_bounds__(320) void attn_part(const float* __restrict__ qp,
                                                 const float* __restrict__ kp,
                                                 const float* __restrict__ vp,
                                                 const int* __restrict__ topIdx,
                                                 float* __restrict__ mPart,
                                                 float* __restrict__ sPart,
                                                 float* __restrict__ oPart) {
    const int blk = blockIdx.x;  // 512 = i*16 + c
    const int i = blk >> 4, c = blk & 15;
    const int b = i >> 3, h = i & 7;
    const int t = threadIdx.x;

    __shared__ float Qs[40][32];
    __shared__ float Vs[128][VSP];
    __shared__ float sc[40][SCP2];
    __shared__ float mred[40], sred[40];

    {
        const int r = t >> 3, qq = t & 7;
        const int lq = topIdx[i * 40 + r];
        *(float4*)&Qs[r][qq * 4] = *(const float4*)(qp + ((size_t)i * 2048 + lq) * 32 + qq * 4);
    }
    for (int e = t; e < 1024; e += 320) {
        const int r = e >> 3, qq = e & 7;
        *(float4*)&Vs[r][qq * 4] =
            *(const float4*)(vp + (size_t)b * LD_ + (size_t)(c * 128 + r) * 256 + h * 32 + qq * 4);
    }
    __syncthreads();

    const float scale = 0.17677669529663687f;  // 1/sqrt(32)

    if (t < 256) {
        const int r = t >> 1;
        const int j0 = (t & 1) * 20;
        const float* kr = kp + (size_t)b * LD_ + (size_t)(c * 128 + r) * 256 + h * 32;
        float kv[32];
#pragma unroll
        for (int z = 0; z < 8; ++z) {
            float4 x = *(const float4*)(kr + z * 4);
            kv[4 * z] = x.x; kv[4 * z + 1] = x.y; kv[4 * z + 2] = x.z; kv[4 * z + 3] = x.w;
        }
#pragma unroll 4
        for (int jj = 0; jj < 20; ++jj) {
            const int j = j0 + jj;
            float a0 = 0, a1 = 0, a2 = 0, a3 = 0;
#pragma unroll
            for (int z = 0; z < 8; ++z) {
                const float4 q4 = *(const float4*)&Qs[j][z * 4];
                a0 = fmaf(kv[4 * z], q4.x, a0);
                a1 = fmaf(kv[4 * z + 1], q4.y, a1);
                a2 = fmaf(kv[4 * z + 2], q4.z, a2);
                a3 = fmaf(kv[4 * z + 3], q4.w, a3);
            }
            sc[j][r] = ((a0 + a1) + (a2 + a3)) * scale;
        }
    }
    __syncthreads();

    {
        const int w = t >> 6, lane = t & 63;
#pragma unroll
        for (int rr = 0; rr < 8; ++rr) {
            const int j = w * 8 + rr;
            float x0 = sc[j][lane], x1 = sc[j][lane + 64];
            float m = fmaxf(x0, x1);
#pragma unroll
            for (int off = 1; off < 64; off <<= 1) m = fmaxf(m, __shfl_xor(m, off, 64));
            const float e0 = __expf(x0 - m), e1 = __expf(x1 - m);
            sc[j][lane] = e0; sc[j][lane + 64] = e1;
            float s = e0 + e1;
#pragma unroll
            for (int off = 1; off < 64; off <<= 1) s += __shfl_xor(s, off, 64);
            if (lane == 0) { mred[j] = m; sred[j] = s; }
        }
    }
    __syncthreads();

    {
        const int j = t >> 3, qq = t & 7;
        float4 acc = make_float4(0.f, 0.f, 0.f, 0.f);
        for (int l = 0; l < 128; ++l) {
            const float p = sc[j][l];
            const float4 v4 = *(const float4*)&Vs[l][qq * 4];
            acc.x = fmaf(p, v4.x, acc.x);
            acc.y = fmaf(p, v4.y, acc.y);
            acc.z = fmaf(p, v4.z, acc.z);
            acc.w = fmaf(p, v4.w, acc.w);
        }
        const size_t o = (size_t)(i * NCH_ + c) * 40 + j;
        *(float4*)&oPart[o * 32 + qq * 4] = acc;
        if (qq == 0) { mPart[o] = mred[j]; sPart[o] = sred[j]; }
    }
}

// ---------------------------------------------------------------------------
// Merge the 16 chunk partials per (i,j) with softmax rescaling. 32 blocks.
// ---------------------------------------------------------------------------
__global__ __launch_bounds__(256) void attn_combine(const float* __restrict__ mPart,
                                                    const float* __restrict__ sPart,
                                                    const float* __restrict__ oPart,
                                                    float* __restrict__ attnOut) {
    const int i = blockIdx.x;
    const int b = i >> 3, h = i & 7;
    const int t = threadIdx.x;
    for (int e = t; e < 1280; e += 256) {
        const int j = e >> 5, d = e & 31;
        float mv[NCH_];
        float M = -INFINITY;
#pragma unroll
        for (int c = 0; c < NCH_; ++c) {
            mv[c] = mPart[(size_t)(i * NCH_ + c) * 40 + j];
            M = fmaxf(M, mv[c]);
        }
        float S = 0.f, O = 0.f;
#pragma unroll
        for (int c = 0; c < NCH_; ++c) {
            const float sc_ = __expf(mv[c] - M);
            const size_t o = (size_t)(i * NCH_ + c) * 40 + j;
            S = fmaf(sPart[o], sc_, S);
            O = fmaf(oPart[o * 32 + d], sc_, O);
        }
        attnOut[((size_t)b * 40 + j) * 256 + h * 32 + d] = O / S;
    }
}

// ---------------------------------------------------------------------------
extern "C" void kernel_launch(void* const* d_in, const int* in_sizes, int n_in,
                              void* d_out, int out_size, void* d_ws, size_t ws_size,
                              hipStream_t stream) {
    const float* q  = (const float*)d_in[0];
    const float* k  = (const float*)d_in[1];
    const float* v  = (const float*)d_in[2];
    const float* Wq = (const float*)d_in[3];
    const float* bq = (const float*)d_in[4];
    const float* Wk = (const float*)d_in[5];
    const float* bk = (const float*)d_in[6];
    const float* Wv = (const float*)d_in[7];
    const float* bv = (const float*)d_in[8];
    const float* Wc = (const float*)d_in[9];
    const float* bc = (const float*)d_in[10];
    const int* idx  = (const int*)d_in[11];
    float* out = (float*)d_out;

    // Workspace map (peak ~32.9 MB):
    //  [0,8)MB qp | [8,16) kp | [16,24) vp
    //  [24,28) Khi; later mPart/sPart/oPart (attn partials, 2.8 MB)
    //  [28,32) Klo
    //  32M+0 Mv(256K) | +256K Qmean(256K) | +512K Ksum32(128K)
    //  +640K candIdx(8K) | +648K topIdx(8K) | +656K refPart(64K)
    //  +720K attnOut(160K)
    char* w = (char*)d_ws;
    float*          qp      = (float*)(w);
    float*          kp      = (float*)(w + (8u << 20));
    float*          vp      = (float*)(w + (16u << 20));
    unsigned short* Khi     = (unsigned short*)(w + (24u << 20));
    unsigned short* Klo     = (unsigned short*)(w + (28u << 20));
    float*          Mv      = (float*)(w + (32u << 20));
    float*          Qmean   = (float*)(w + (32u << 20) + (256u << 10));
    float*          Ksum32  = (float*)(w + (32u << 20) + (512u << 10));
    int*            candIdx = (int*)  (w + (32u << 20) + (640u << 10));
    int*            topIdx  = (int*)  (w + (32u << 20) + (648u << 10));
    float*          refPart = (float*)(w + (32u << 20) + (656u << 10));
    float*          attnOut = (float*)(w + (32u << 20) + (720u << 10));
    float*          mPart   = (float*)(w + (24u << 20));                // after mpart_mfma
    float*          sPart   = (float*)(w + (24u << 20) + (128u << 10));
    float*          oPart   = (float*)(w + (24u << 20) + (256u << 10)); // 2.62 MB

    // 9 launches.
    hipLaunchKernelGGL(gemm_mfma3, dim3(64, 4, 3), dim3(256), 0, stream,
                       q, k, v, Wq, Wk, Wv, bq, bk, bv, qp, kp, vp);
    hipLaunchKernelGGL(kconv_ksum, dim3(1024), dim3(256), 0, stream, kp, idx, Khi, Klo, Ksum32);
    hipLaunchKernelGGL(mpart_mfma, dim3(1024), dim3(256), 0, stream, qp, Khi, Klo, Ksum32, Mv, Qmean);
    hipLaunchKernelGGL(topk64_kernel, dim3(32), dim3(256), 0, stream, Mv, candIdx);
    hipLaunchKernelGGL(refine_kernel, dim3(256), dim3(256), 0, stream, qp, kp, idx, candIdx, refPart);
    hipLaunchKernelGGL(select40_kernel, dim3(32), dim3(64), 0, stream, candIdx, refPart, Qmean, topIdx);
    hipLaunchKernelGGL(attn_part, dim3(512), dim3(320), 0, stream, qp, kp, vp, topIdx, mPart, sPart, oPart);
    hipLaunchKernelGGL(attn_combine, dim3(32), dim3(256), 0, stream, mPart, sPart, oPart, attnOut);
    hipLaunchKernelGGL(gemm_out, dim3(2, 4), dim3(256), 0, stream, attnOut, Wc, bc, out);
}

// Round 15
// 246.901 us; speedup vs baseline: 1.0776x; 1.0213x over previous
//
#include <hip/hip_runtime.h>
#include <math.h>

// Problem constants
#define B_ 4
#define L_ 2048
#define D_ 256
#define H_ 8
#define DH_ 32
#define NH_ 32           // B*H
#define U_ 40
#define LD_ 524288       // L_*D_ floats per batch
#define NCH_ 16          // attention L-chunks

typedef __attribute__((ext_vector_type(8))) short short8;
typedef __attribute__((ext_vector_type(4))) float floatx4;

static __device__ __forceinline__ unsigned long long ullmin_(unsigned long long a, unsigned long long b) {
    return a < b ? a : b;
}
static __device__ __forceinline__ unsigned short f2bf_rne(float x) {
    unsigned u = __float_as_uint(x);
    unsigned r = u + 0x7FFFu + ((u >> 16) & 1u);
    return (unsigned short)(r >> 16);
}
static __device__ __forceinline__ float bf2f(unsigned short h) {
    return __uint_as_float(((unsigned)h) << 16);
}

// ---------------------------------------------------------------------------
// Batched projection GEMM with INLINE weight conversion.
// Grid (64, 4, 3): block = 128 rows x 64 cols; 768 blocks.
// 3-way-split bf16, 6 MFMA terms; per-dot err ~2e-7.
// ---------------------------------------------------------------------------
__global__ __launch_bounds__(256) void gemm_mfma3(const float* __restrict__ q,
                                                  const float* __restrict__ k,
                                                  const float* __restrict__ v,
                                                  const float* __restrict__ Wq,
                                                  const float* __restrict__ Wk,
                                                  const float* __restrict__ Wv,
                                                  const float* __restrict__ bq,
                                                  const float* __restrict__ bk,
                                                  const float* __restrict__ bv,
                                                  float* __restrict__ qp,
                                                  float* __restrict__ kp,
                                                  float* __restrict__ vp) {
    const int mat = blockIdx.z;
    const float* X = (mat == 0) ? q : (mat == 1) ? k : v;
    const float* W = (mat == 0) ? Wq : (mat == 1) ? Wk : Wv;
    const float* bias = (mat == 0) ? bq : (mat == 1) ? bk : bv;
    float* Y = (mat == 0) ? qp : (mat == 1) ? kp : vp;

    const int t = threadIdx.x;
    const int w = t >> 6, lane = t & 63;
    const int lq = lane & 15, quad = lane >> 4;
    const int colBase = blockIdx.y * 64;
    const int rowBaseW = blockIdx.x * 128 + w * 32;  // wave owns 2 m-tiles

    __shared__ unsigned short Bls[24576];  // 48 KB

    floatx4 acc[2][4];
#pragma unroll
    for (int mt = 0; mt < 2; ++mt)
#pragma unroll
        for (int nt = 0; nt < 4; ++nt) acc[mt][nt] = (floatx4){0.f, 0.f, 0.f, 0.f};

    for (int phase = 0; phase < 2; ++phase) {
        __syncthreads();
#pragma unroll
        for (int r = 0; r < 8; ++r) {
            const int e = t + 256 * r;      // 0..2047
            const int col = e >> 5;
            const int k4u = e & 31;
            const int kk = phase * 128 + k4u * 4;
            const float4 x = *(const float4*)(W + (size_t)(colBase + col) * 256 + kk);
            float xs[4] = {x.x, x.y, x.z, x.w};
            unsigned short hv[4], mv4[4], lv[4];
#pragma unroll
            for (int j = 0; j < 4; ++j) {
                hv[j] = f2bf_rne(xs[j]);
                const float e1 = xs[j] - bf2f(hv[j]);
                mv4[j] = f2bf_rne(e1);
                const float e2 = e1 - bf2f(mv4[j]);
                lv[j] = f2bf_rne(e2);
            }
            const int nt = col >> 4, cin = col & 15;
            const int ktl = k4u >> 3, kin = (k4u & 7) * 4;
            const int base = nt * 512 + cin * 32 + kin;
            *(ushort4*)&Bls[((0 * 4 + ktl) << 11) + base] = make_ushort4(hv[0], hv[1], hv[2], hv[3]);
            *(ushort4*)&Bls[((1 * 4 + ktl) << 11) + base] = make_ushort4(mv4[0], mv4[1], mv4[2], mv4[3]);
            *(ushort4*)&Bls[((2 * 4 + ktl) << 11) + base] = make_ushort4(lv[0], lv[1], lv[2], lv[3]);
        }
        __syncthreads();

#pragma unroll
        for (int ktl = 0; ktl < 4; ++ktl) {
            const int kt = phase * 4 + ktl;
            short8 Bh[4], Bm[4], Bl[4];
            const int fo = lq * 32 + quad * 8;
#pragma unroll
            for (int j = 0; j < 4; ++j) {
                Bh[j] = *(const short8*)&Bls[((0 * 4 + ktl) << 11) + j * 512 + fo];
                Bm[j] = *(const short8*)&Bls[((1 * 4 + ktl) << 11) + j * 512 + fo];
                Bl[j] = *(const short8*)&Bls[((2 * 4 + ktl) << 11) + j * 512 + fo];
            }
#pragma unroll
            for (int mt = 0; mt < 2; ++mt) {
                const int m = rowBaseW + mt * 16 + lq;
                short8 Ah, Am, Al;
                {
                    const float* xr = X + (size_t)m * 256 + kt * 32 + quad * 8;
                    const float4 x0 = *(const float4*)xr;
                    const float4 x1 = *(const float4*)(xr + 4);
                    float xs[8] = {x0.x, x0.y, x0.z, x0.w, x1.x, x1.y, x1.z, x1.w};
#pragma unroll
                    for (int j = 0; j < 8; ++j) {
                        const unsigned short h = f2bf_rne(xs[j]);
                        const float e1 = xs[j] - bf2f(h);
                        const unsigned short md = f2bf_rne(e1);
                        const float e2 = e1 - bf2f(md);
                        Ah[j] = (short)h;
                        Am[j] = (short)md;
                        Al[j] = (short)f2bf_rne(e2);
                    }
                }
#pragma unroll
                for (int j = 0; j < 4; ++j) {
                    floatx4 a = acc[mt][j];
                    a = __builtin_amdgcn_mfma_f32_16x16x32_bf16(Am, Bm[j], a, 0, 0, 0);
                    a = __builtin_amdgcn_mfma_f32_16x16x32_bf16(Ah, Bl[j], a, 0, 0, 0);
                    a = __builtin_amdgcn_mfma_f32_16x16x32_bf16(Al, Bh[j], a, 0, 0, 0);
                    a = __builtin_amdgcn_mfma_f32_16x16x32_bf16(Ah, Bm[j], a, 0, 0, 0);
                    a = __builtin_amdgcn_mfma_f32_16x16x32_bf16(Am, Bh[j], a, 0, 0, 0);
                    a = __builtin_amdgcn_mfma_f32_16x16x32_bf16(Ah, Bh[j], a, 0, 0, 0);
                    acc[mt][j] = a;
                }
            }
        }
    }

#pragma unroll
    for (int mt = 0; mt < 2; ++mt)
#pragma unroll
        for (int nt = 0; nt < 4; ++nt) {
            const int c = colBase + nt * 16 + lq;
            const float bv_ = bias[c];
#pragma unroll
            for (int r = 0; r < 4; ++r) {
                const int mr = rowBaseW + mt * 16 + quad * 4 + r;
                Y[(size_t)mr * 256 + c] = acc[mt][nt][r] + bv_;
            }
        }
}

// ---------------------------------------------------------------------------
// Final-projection GEMM v3 (M=160): grid (10,4) = 40 one-wave blocks.
// NO LDS: each lane loads its B fragment Wc[col][kt*32+quad*8..+8] directly
// (contiguous 32 B, L2-resident) and 3-way-splits in registers. Values are
// bit-identical to the LDS-staged version (same RNE splits, same MFMA order).
// Round-14's (2,4) grid = 8 blocks was the last parallelism-starved kernel.
// ---------------------------------------------------------------------------
__global__ __launch_bounds__(64) void gemm_out(const float* __restrict__ X,
                                               const float* __restrict__ Wc,
                                               const float* __restrict__ bias,
                                               float* __restrict__ Y) {
    const int lane = threadIdx.x;
    const int lq = lane & 15, quad = lane >> 4;
    const int rowBase = blockIdx.x * 16;   // 160 = 10*16 exact
    const int colBase = blockIdx.y * 64;

    floatx4 acc[4];
#pragma unroll
    for (int nt = 0; nt < 4; ++nt) acc[nt] = (floatx4){0.f, 0.f, 0.f, 0.f};

#pragma unroll
    for (int kt = 0; kt < 8; ++kt) {
        short8 Ah, Am, Al;
        {
            const float* xr = X + (size_t)(rowBase + lq) * 256 + kt * 32 + quad * 8;
            const float4 x0 = *(const float4*)xr;
            const float4 x1 = *(const float4*)(xr + 4);
            float xs[8] = {x0.x, x0.y, x0.z, x0.w, x1.x, x1.y, x1.z, x1.w};
#pragma unroll
            for (int j = 0; j < 8; ++j) {
                const unsigned short h = f2bf_rne(xs[j]);
                const float e1 = xs[j] - bf2f(h);
                const unsigned short md = f2bf_rne(e1);
                const float e2 = e1 - bf2f(md);
                Ah[j] = (short)h;
                Am[j] = (short)md;
                Al[j] = (short)f2bf_rne(e2);
            }
        }
        short8 Bh[4], Bm[4], Bl[4];
#pragma unroll
        for (int nt = 0; nt < 4; ++nt) {
            const float* wr = Wc + (size_t)(colBase + nt * 16 + lq) * 256 + kt * 32 + quad * 8;
            const float4 x0 = *(const float4*)wr;
            const float4 x1 = *(const float4*)(wr + 4);
            float xs[8] = {x0.x, x0.y, x0.z, x0.w, x1.x, x1.y, x1.z, x1.w};
#pragma unroll
            for (int j = 0; j < 8; ++j) {
                const unsigned short h = f2bf_rne(xs[j]);
                const float e1 = xs[j] - bf2f(h);
                const unsigned short md = f2bf_rne(e1);
                const float e2 = e1 - bf2f(md);
                Bh[nt][j] = (short)h;
                Bm[nt][j] = (short)md;
                Bl[nt][j] = (short)f2bf_rne(e2);
            }
        }
#pragma unroll
        for (int nt = 0; nt < 4; ++nt) {
            floatx4 a = acc[nt];
            a = __builtin_amdgcn_mfma_f32_16x16x32_bf16(Am, Bm[nt], a, 0, 0, 0);
            a = __builtin_amdgcn_mfma_f32_16x16x32_bf16(Ah, Bl[nt], a, 0, 0, 0);
            a = __builtin_amdgcn_mfma_f32_16x16x32_bf16(Al, Bh[nt], a, 0, 0, 0);
            a = __builtin_amdgcn_mfma_f32_16x16x32_bf16(Ah, Bm[nt], a, 0, 0, 0);
            a = __builtin_amdgcn_mfma_f32_16x16x32_bf16(Am, Bh[nt], a, 0, 0, 0);
            a = __builtin_amdgcn_mfma_f32_16x16x32_bf16(Ah, Bh[nt], a, 0, 0, 0);
            acc[nt] = a;
        }
    }

    // C layout: col = lane&15, row = quad*4+reg
#pragma unroll
    for (int nt = 0; nt < 4; ++nt) {
        const int c = colBase + nt * 16 + lq;
        const float bv = bias[c];
#pragma unroll
        for (int r = 0; r < 4; ++r) {
            const int mr = rowBase + quad * 4 + r;
            Y[(size_t)mr * 256 + c] = acc[nt][r] + bv;
        }
    }
}

// ---------------------------------------------------------------------------
// kconv + ksum partials, 1024 blocks (i*32 + uc), 64 u each.
// ---------------------------------------------------------------------------
__global__ __launch_bounds__(256) void kconv_ksum(const float* __restrict__ kp,
                                                  const int* __restrict__ idx,
                                                  unsigned short* __restrict__ Khi,
                                                  unsigned short* __restrict__ Klo,
                                                  float* __restrict__ Ksum32) {
    const int blk = blockIdx.x;  // 1024: i*32 + uc
    const int i = blk >> 5, uc = blk & 31;
    const int b = i >> 3, h = i & 7;
    const int t = threadIdx.x;
    const int dq = (t & 7) * 4;
    const int ur = t >> 3;  // 0..31

    __shared__ float part[32][36];
    float ksum[4] = {0.f, 0.f, 0.f, 0.f};

#pragma unroll
    for (int p = 0; p < 2; ++p) {
        int u = uc * 64 + p * 32 + ur;
        const float4 x = *(const float4*)(kp + (size_t)b * LD_ + (size_t)idx[u] * D_ + h * DH_ + dq);
        float xs[4] = {x.x, x.y, x.z, x.w};
        unsigned short hv[4], lv[4];
#pragma unroll
        for (int j = 0; j < 4; ++j) {
            ksum[j] += xs[j];
            hv[j] = f2bf_rne(xs[j]);
            lv[j] = f2bf_rne(xs[j] - bf2f(hv[j]));
        }
        size_t o = ((size_t)i * 2048 + u) * 32 + dq;
        *(ushort4*)(Khi + o) = make_ushort4(hv[0], hv[1], hv[2], hv[3]);
        *(ushort4*)(Klo + o) = make_ushort4(lv[0], lv[1], lv[2], lv[3]);
    }
#pragma unroll
    for (int j = 0; j < 4; ++j) part[ur][dq + j] = ksum[j];
    __syncthreads();
    if (t < 32) {
        float s = 0.f;
#pragma unroll 8
        for (int u2 = 0; u2 < 32; ++u2) s += part[u2][t];
        Ksum32[(size_t)blk * 32 + t] = s;
    }
}

// ---------------------------------------------------------------------------
// Approx M-sweep on MFMA + fused Ssum reduce (32 partials) + mcombine.
// ---------------------------------------------------------------------------
__global__ __launch_bounds__(256) void mpart_mfma(const float* __restrict__ qp,
                                                  const unsigned short* __restrict__ Khi,
                                                  const unsigned short* __restrict__ Klo,
                                                  const float* __restrict__ Ksum32,
                                                  float* __restrict__ Mv,
                                                  float* __restrict__ Qmean) {
    const int blk = blockIdx.x;
    const int i = blk >> 5;
    const int lg = blk & 31;
    const int t = threadIdx.x;
    const int w = t >> 6;
    const int lane = t & 63;
    const int lq = lane & 15;
    const int quad = lane >> 4;

    __shared__ float ssum[32];
    __shared__ float red[4][64];
    if (t < 32) {
        float s = 0.f;
#pragma unroll 8
        for (int uc = 0; uc < 32; ++uc) s += Ksum32[((size_t)i * 32 + uc) * 32 + t];
        ssum[t] = s;
    }

    short8 Ah[4], Al[4];
#pragma unroll
    for (int lt = 0; lt < 4; ++lt) {
        const int l = lg * 64 + lt * 16 + lq;
        const float* qrow = qp + ((size_t)i * 2048 + l) * 32 + quad * 8;
        float4 x0 = *(const float4*)(qrow);
        float4 x1 = *(const float4*)(qrow + 4);
        float xs[8] = {x0.x, x0.y, x0.z, x0.w, x1.x, x1.y, x1.z, x1.w};
#pragma unroll
        for (int j = 0; j < 8; ++j) {
            unsigned short h = f2bf_rne(xs[j]);
            unsigned short lo = f2bf_rne(xs[j] - bf2f(h));
            Ah[lt][j] = (short)h;
            Al[lt][j] = (short)lo;
        }
    }

    floatx4 rmax[4];
#pragma unroll
    for (int lt = 0; lt < 4; ++lt)
        rmax[lt] = (floatx4){-INFINITY, -INFINITY, -INFINITY, -INFINITY};

    const size_t kfrag = ((size_t)i * 2048 + w * 512 + lq) * 32 + quad * 8;
    const unsigned short* ph = Khi + kfrag;
    const unsigned short* pl = Klo + kfrag;
#pragma unroll 2
    for (int s = 0; s < 32; ++s) {
        short8 Bh = *(const short8*)(ph + (size_t)s * 512);
        short8 Bl = *(const short8*)(pl + (size_t)s * 512);
#pragma unroll
        for (int lt = 0; lt < 4; ++lt) {
            floatx4 acc = (floatx4){0.f, 0.f, 0.f, 0.f};
            acc = __builtin_amdgcn_mfma_f32_16x16x32_bf16(Al[lt], Bh, acc, 0, 0, 0);
            acc = __builtin_amdgcn_mfma_f32_16x16x32_bf16(Ah[lt], Bl, acc, 0, 0, 0);
            acc = __builtin_amdgcn_mfma_f32_16x16x32_bf16(Ah[lt], Bh, acc, 0, 0, 0);
#pragma unroll
            for (int r = 0; r < 4; ++r) rmax[lt][r] = fmaxf(rmax[lt][r], acc[r]);
        }
    }

#pragma unroll
    for (int lt = 0; lt < 4; ++lt)
#pragma unroll
        for (int r = 0; r < 4; ++r) {
            float v = rmax[lt][r];
#pragma unroll
            for (int off = 1; off < 16; off <<= 1)
                v = fmaxf(v, __shfl_xor(v, off, 64));
            rmax[lt][r] = v;
        }
    if (lq == 0) {
#pragma unroll
        for (int lt = 0; lt < 4; ++lt)
#pragma unroll
            for (int r = 0; r < 4; ++r)
                red[w][lt * 16 + quad * 4 + r] = rmax[lt][r];
    }
    __syncthreads();
    if (t < 64) {
        const int l = lg * 64 + t;
        float m = fmaxf(fmaxf(red[0][t], red[1][t]), fmaxf(red[2][t], red[3][t]));
        const float4* q4 = (const float4*)(qp + ((size_t)i * 2048 + l) * 32);
        const float4* s4 = (const float4*)ssum;
        float qs = 0.f;
#pragma unroll
        for (int z = 0; z < 8; ++z) {
            float4 a = q4[z];
            float4 c = s4[z];
            qs = fmaf(a.x, c.x, qs);
            qs = fmaf(a.y, c.y, qs);
            qs = fmaf(a.z, c.z, qs);
            qs = fmaf(a.w, c.w, qs);
        }
        const float qm = qs * (1.0f / 2048.0f);
        Qmean[(size_t)i * 2048 + l] = qm;
        Mv[(size_t)i * 2048 + l] = m - qm;
    }
}

// ---------------------------------------------------------------------------
// Bottom-64 candidates per i from approx Mv. Keys in registers.
// ---------------------------------------------------------------------------
__global__ __launch_bounds__(256) void topk64_kernel(const float* __restrict__ Mv,
                                                     int* __restrict__ candIdx) {
    const int i = blockIdx.x;
    const int t = threadIdx.x;
    unsigned long long keys[8];
    __shared__ unsigned long long wred[4];
#pragma unroll
    for (int j = 0; j < 8; ++j) {
        const int l = t + 256 * j;
        unsigned u32 = __float_as_uint(Mv[(size_t)i * 2048 + l]);
        u32 = (u32 & 0x80000000u) ? ~u32 : (u32 | 0x80000000u);
        keys[j] = ((unsigned long long)u32 << 32) | (unsigned)l;
    }
    for (int it = 0; it < 64; ++it) {
        unsigned long long best = keys[0];
#pragma unroll
        for (int j = 1; j < 8; ++j) best = ullmin_(best, keys[j]);
#pragma unroll
        for (int off = 1; off < 64; off <<= 1)
            best = ullmin_(best, __shfl_xor(best, off, 64));
        if ((t & 63) == 0) wred[t >> 6] = best;
        __syncthreads();
        const unsigned long long m = ullmin_(ullmin_(wred[0], wred[1]), ullmin_(wred[2], wred[3]));
        if (t == 0) candIdx[i * 64 + it] = (int)(m & 0xffffffffu);
#pragma unroll
        for (int j = 0; j < 8; ++j)
            if (keys[j] == m) keys[j] = ~0ULL;
        __syncthreads();
    }
}

// ---------------------------------------------------------------------------
// Exact fp32 refine: grid 256 = i*8 + chunk (256 u each).
// ---------------------------------------------------------------------------
__global__ __launch_bounds__(256) void refine_kernel(const float* __restrict__ qp,
                                                     const float* __restrict__ kp,
                                                     const int* __restrict__ idx,
                                                     const int* __restrict__ candIdx,
                                                     float* __restrict__ refPart) {
    const int blk = blockIdx.x;  // 256
    const int i = blk >> 3, c = blk & 7;
    const int b = i >> 3, h = i & 7;
    const int t = threadIdx.x;
    __shared__ float qc[64][40];
    __shared__ float Ks[128][40];

    {
        const int cand = t >> 2, dp = (t & 3) * 8;
        const int l = candIdx[i * 64 + cand];
        const float* src = qp + ((size_t)i * 2048 + l) * 32 + dp;
        *(float4*)&qc[cand][dp] = *(const float4*)(src);
        *(float4*)&qc[cand][dp + 4] = *(const float4*)(src + 4);
    }
    __syncthreads();

    const int cand = t >> 2, usub = t & 3;
    float qv[32];
#pragma unroll
    for (int z = 0; z < 8; ++z) {
        float4 a = *(const float4*)&qc[cand][z * 4];
        qv[4 * z] = a.x; qv[4 * z + 1] = a.y; qv[4 * z + 2] = a.z; qv[4 * z + 3] = a.w;
    }

    float m = -INFINITY;
    for (int s = 0; s < 2; ++s) {
        {
            const int r = t >> 1, half = t & 1;
            const int u = c * 256 + s * 128 + r;
            const float* krow = kp + (size_t)b * LD_ + (size_t)idx[u] * D_ + h * DH_ + half * 16;
#pragma unroll
            for (int z = 0; z < 4; ++z)
                *(float4*)&Ks[r][half * 16 + z * 4] = *(const float4*)(krow + z * 4);
        }
        __syncthreads();
        for (int ur = usub; ur < 128; ur += 4) {
            float a0 = 0, a1 = 0, a2 = 0, a3 = 0;
#pragma unroll
            for (int z = 0; z < 8; ++z) {
                float4 kv = *(const float4*)&Ks[ur][z * 4];
                a0 = fmaf(qv[4 * z], kv.x, a0);
                a1 = fmaf(qv[4 * z + 1], kv.y, a1);
                a2 = fmaf(qv[4 * z + 2], kv.z, a2);
                a3 = fmaf(qv[4 * z + 3], kv.w, a3);
            }
            m = fmaxf(m, (a0 + a1) + (a2 + a3));
        }
        __syncthreads();
    }
    m = fmaxf(m, __shfl_xor(m, 1, 64));
    m = fmaxf(m, __shfl_xor(m, 2, 64));
    if ((t & 3) == 0) refPart[((size_t)i * 8 + c) * 64 + cand] = m;
}

// ---------------------------------------------------------------------------
// Final exact top-40 from 64 candidates (8 refine chunks). One wave per i.
// ---------------------------------------------------------------------------
__global__ __launch_bounds__(64) void select40_kernel(const int* __restrict__ candIdx,
                                                      const float* __restrict__ refPart,
                                                      const float* __restrict__ Qmean,
                                                      int* __restrict__ topIdx) {
    const int i = blockIdx.x;
    const int t = threadIdx.x;
    const int l = candIdx[i * 64 + t];
    float m = -INFINITY;
#pragma unroll
    for (int c = 0; c < 8; ++c) m = fmaxf(m, refPart[((size_t)i * 8 + c) * 64 + t]);
    float Mex = m - Qmean[(size_t)i * 2048 + l];
    unsigned u32 = __float_as_uint(Mex);
    u32 = (u32 & 0x80000000u) ? ~u32 : (u32 | 0x80000000u);
    unsigned long long key = ((unsigned long long)u32 << 32) | (unsigned)l;
    for (int it = 0; it < 40; ++it) {
        unsigned long long k2 = key;
#pragma unroll
        for (int off = 1; off < 64; off <<= 1) k2 = ullmin_(k2, __shfl_xor(k2, off, 64));
        if (key == k2) {
            topIdx[i * 40 + it] = l;
            key = ~0ULL;
        }
    }
}

// ---------------------------------------------------------------------------
// Flash-style attention, split over L into 16 chunks of 128 rows.
// Grid: 512 = i*16 + c, 320 threads.
// ---------------------------------------------------------------------------
#define SCP2 136  // sc row pad
#define VSP 36    // Vs row pad

__global__ __launch_bounds__(320) void attn_part(const float* __restrict__ qp,
                                                 const float* __restrict__ kp,
                                                 const float* __restrict__ vp,
                                                 const int* __restrict__ topIdx,
                                                 float* __restrict__ mPart,
                                                 float* __restrict__ sPart,
                                                 float* __restrict__ oPart) {
    const int blk = blockIdx.x;  // 512 = i*16 + c
    const int i = blk >> 4, c = blk & 15;
    const int b = i >> 3, h = i & 7;
    const int t = threadIdx.x;

    __shared__ float Qs[40][32];
    __shared__ float Vs[128][VSP];
    __shared__ float sc[40][SCP2];
    __shared__ float mred[40], sred[40];

    {
        const int r = t >> 3, qq = t & 7;
        const int lq = topIdx[i * 40 + r];
        *(float4*)&Qs[r][qq * 4] = *(const float4*)(qp + ((size_t)i * 2048 + lq) * 32 + qq * 4);
    }
    for (int e = t; e < 1024; e += 320) {
        const int r = e >> 3, qq = e & 7;
        *(float4*)&Vs[r][qq * 4] =
            *(const float4*)(vp + (size_t)b * LD_ + (size_t)(c * 128 + r) * 256 + h * 32 + qq * 4);
    }
    __syncthreads();

    const float scale = 0.17677669529663687f;  // 1/sqrt(32)

    if (t < 256) {
        const int r = t >> 1;
        const int j0 = (t & 1) * 20;
        const float* kr = kp + (size_t)b * LD_ + (size_t)(c * 128 + r) * 256 + h * 32;
        float kv[32];
#pragma unroll
        for (int z = 0; z < 8; ++z) {
            float4 x = *(const float4*)(kr + z * 4);
            kv[4 * z] = x.x; kv[4 * z + 1] = x.y; kv[4 * z + 2] = x.z; kv[4 * z + 3] = x.w;
        }
#pragma unroll 4
        for (int jj = 0; jj < 20; ++jj) {
            const int j = j0 + jj;
            float a0 = 0, a1 = 0, a2 = 0, a3 = 0;
#pragma unroll
            for (int z = 0; z < 8; ++z) {
                const float4 q4 = *(const float4*)&Qs[j][z * 4];
                a0 = fmaf(kv[4 * z], q4.x, a0);
                a1 = fmaf(kv[4 * z + 1], q4.y, a1);
                a2 = fmaf(kv[4 * z + 2], q4.z, a2);
                a3 = fmaf(kv[4 * z + 3], q4.w, a3);
            }
            sc[j][r] = ((a0 + a1) + (a2 + a3)) * scale;
        }
    }
    __syncthreads();

    {
        const int w = t >> 6, lane = t & 63;
#pragma unroll
        for (int rr = 0; rr < 8; ++rr) {
            const int j = w * 8 + rr;
            float x0 = sc[j][lane], x1 = sc[j][lane + 64];
            float m = fmaxf(x0, x1);
#pragma unroll
            for (int off = 1; off < 64; off <<= 1) m = fmaxf(m, __shfl_xor(m, off, 64));
            const float e0 = __expf(x0 - m), e1 = __expf(x1 - m);
            sc[j][lane] = e0; sc[j][lane + 64] = e1;
            float s = e0 + e1;
#pragma unroll
            for (int off = 1; off < 64; off <<= 1) s += __shfl_xor(s, off, 64);
            if (lane == 0) { mred[j] = m; sred[j] = s; }
        }
    }
    __syncthreads();

    {
        const int j = t >> 3, qq = t & 7;
        float4 acc = make_float4(0.f, 0.f, 0.f, 0.f);
        for (int l = 0; l < 128; ++l) {
            const float p = sc[j][l];
            const float4 v4 = *(const float4*)&Vs[l][qq * 4];
            acc.x = fmaf(p, v4.x, acc.x);
            acc.y = fmaf(p, v4.y, acc.y);
            acc.z = fmaf(p, v4.z, acc.z);
            acc.w = fmaf(p, v4.w, acc.w);
        }
        const size_t o = (size_t)(i * NCH_ + c) * 40 + j;
        *(float4*)&oPart[o * 32 + qq * 4] = acc;
        if (qq == 0) { mPart[o] = mred[j]; sPart[o] = sred[j]; }
    }
}

// ---------------------------------------------------------------------------
// Merge the 16 chunk partials per (i,j) with softmax rescaling. 32 blocks.
// ---------------------------------------------------------------------------
__global__ __launch_bounds__(256) void attn_combine(const float* __restrict__ mPart,
                                                    const float* __restrict__ sPart,
                                                    const float* __restrict__ oPart,
                                                    float* __restrict__ attnOut) {
    const int i = blockIdx.x;
    const int b = i >> 3, h = i & 7;
    const int t = threadIdx.x;
    for (int e = t; e < 1280; e += 256) {
        const int j = e >> 5, d = e & 31;
        float mv[NCH_];
        float M = -INFINITY;
#pragma unroll
        for (int c = 0; c < NCH_; ++c) {
            mv[c] = mPart[(size_t)(i * NCH_ + c) * 40 + j];
            M = fmaxf(M, mv[c]);
        }
        float S = 0.f, O = 0.f;
#pragma unroll
        for (int c = 0; c < NCH_; ++c) {
            const float sc_ = __expf(mv[c] - M);
            const size_t o = (size_t)(i * NCH_ + c) * 40 + j;
            S = fmaf(sPart[o], sc_, S);
            O = fmaf(oPart[o * 32 + d], sc_, O);
        }
        attnOut[((size_t)b * 40 + j) * 256 + h * 32 + d] = O / S;
    }
}

// ---------------------------------------------------------------------------
extern "C" void kernel_launch(void* const* d_in, const int* in_sizes, int n_in,
                              void* d_out, int out_size, void* d_ws, size_t ws_size,
                              hipStream_t stream) {
    const float* q  = (const float*)d_in[0];
    const float* k  = (const float*)d_in[1];
    const float* v  = (const float*)d_in[2];
    const float* Wq = (const float*)d_in[3];
    const float* bq = (const float*)d_in[4];
    const float* Wk = (const float*)d_in[5];
    const float* bk = (const float*)d_in[6];
    const float* Wv = (const float*)d_in[7];
    const float* bv = (const float*)d_in[8];
    const float* Wc = (const float*)d_in[9];
    const float* bc = (const float*)d_in[10];
    const int* idx  = (const int*)d_in[11];
    float* out = (float*)d_out;

    // Workspace map (peak ~32.9 MB):
    //  [0,8)MB qp | [8,16) kp | [16,24) vp
    //  [24,28) Khi; later mPart/sPart/oPart (attn partials, 2.8 MB)
    //  [28,32) Klo
    //  32M+0 Mv(256K) | +256K Qmean(256K) | +512K Ksum32(128K)
    //  +640K candIdx(8K) | +648K topIdx(8K) | +656K refPart(64K)
    //  +720K attnOut(160K)
    char* w = (char*)d_ws;
    float*          qp      = (float*)(w);
    float*          kp      = (float*)(w + (8u << 20));
    float*          vp      = (float*)(w + (16u << 20));
    unsigned short* Khi     = (unsigned short*)(w + (24u << 20));
    unsigned short* Klo     = (unsigned short*)(w + (28u << 20));
    float*          Mv      = (float*)(w + (32u << 20));
    float*          Qmean   = (float*)(w + (32u << 20) + (256u << 10));
    float*          Ksum32  = (float*)(w + (32u << 20) + (512u << 10));
    int*            candIdx = (int*)  (w + (32u << 20) + (640u << 10));
    int*            topIdx  = (int*)  (w + (32u << 20) + (648u << 10));
    float*          refPart = (float*)(w + (32u << 20) + (656u << 10));
    float*          attnOut = (float*)(w + (32u << 20) + (720u << 10));
    float*          mPart   = (float*)(w + (24u << 20));                // after mpart_mfma
    float*          sPart   = (float*)(w + (24u << 20) + (128u << 10));
    float*          oPart   = (float*)(w + (24u << 20) + (256u << 10)); // 2.62 MB

    // 9 launches.
    hipLaunchKernelGGL(gemm_mfma3, dim3(64, 4, 3), dim3(256), 0, stream,
                       q, k, v, Wq, Wk, Wv, bq, bk, bv, qp, kp, vp);
    hipLaunchKernelGGL(kconv_ksum, dim3(1024), dim3(256), 0, stream, kp, idx, Khi, Klo, Ksum32);
    hipLaunchKernelGGL(mpart_mfma, dim3(1024), dim3(256), 0, stream, qp, Khi, Klo, Ksum32, Mv, Qmean);
    hipLaunchKernelGGL(topk64_kernel, dim3(32), dim3(256), 0, stream, Mv, candIdx);
    hipLaunchKernelGGL(refine_kernel, dim3(256), dim3(256), 0, stream, qp, kp, idx, candIdx, refPart);
    hipLaunchKernelGGL(select40_kernel, dim3(32), dim3(64), 0, stream, candIdx, refPart, Qmean, topIdx);
    hipLaunchKernelGGL(attn_part, dim3(512), dim3(320), 0, stream, qp, kp, vp, topIdx, mPart, sPart, oPart);
    hipLaunchKernelGGL(attn_combine, dim3(32), dim3(256), 0, stream, mPart, sPart, oPart, attnOut);
    hipLaunchKernelGGL(gemm_out, dim3(10, 4), dim3(64), 0, stream, attnOut, Wc, bc, out);
}